// Round 1
// baseline (1430.777 us; speedup 1.0000x reference)
//
#include <hip/hip_runtime.h>
#include <hip/hip_bf16.h>

// NeXtVLAD forward, fp32 correctness-first implementation.
// Dims fixed by the problem:
#define NN 64
#define MM 300
#define CC 768
#define EE 1536          // LAMB*C
#define GG 8
#define KK 64
#define FF 512           // G*K
#define GS 192           // LAMB*C/G
#define PP 2400          // M*G
#define DESC 12288       // K*GS
#define NMROWS 19200     // N*M
#define NB 512
#define NCLS 701

// ---------------------------------------------------------------------------
// Tiled SGEMM:  C[i,j] = sum_k A[i,k]*B[j,k] + bias[j]   (both K-contiguous)
// MAPA: A rows come from features[:,1:] -> row r maps to (r/300)*301 + r%300 + 1
// BN0:  epilogue v = v*bn_g[r%300] + bn_b[r%300]
// Tile 128x128, BK=16, 256 threads, 8x8 per thread.
// ---------------------------------------------------------------------------
template<bool MAPA, bool BN0>
__global__ __launch_bounds__(256)
void sgemm_nt(const float* __restrict__ A, int lda,
              const float* __restrict__ B, int ldb,
              const float* __restrict__ bias,
              const float* __restrict__ bn_g, const float* __restrict__ bn_b,
              float* __restrict__ C, int Ndim, int Kdim)
{
    __shared__ float As[16][132];
    __shared__ float Bs[16][132];

    const int tid  = threadIdx.x;
    const int tx   = tid & 15;        // -> 8 output cols
    const int ty   = tid >> 4;        // -> 8 output rows
    const int row0 = blockIdx.y * 128;
    const int col0 = blockIdx.x * 128;

    // Each thread loads 2 float4 from A and 2 from B per K-chunk; row/col fixed.
    const int m0 = tid >> 2;          // 0..63
    const int m1 = m0 + 64;
    const int k4 = (tid & 3) << 2;    // 0,4,8,12

    size_t arow0, arow1;
    if (MAPA) {
        int r0 = row0 + m0, r1 = row0 + m1;
        arow0 = (size_t)((r0 / 300) * 301 + (r0 % 300) + 1);
        arow1 = (size_t)((r1 / 300) * 301 + (r1 % 300) + 1);
    } else {
        arow0 = (size_t)(row0 + m0);
        arow1 = (size_t)(row0 + m1);
    }
    const float* aP0 = A + arow0 * lda + k4;
    const float* aP1 = A + arow1 * lda + k4;
    const float* bP0 = B + (size_t)(col0 + m0) * ldb + k4;
    const float* bP1 = B + (size_t)(col0 + m1) * ldb + k4;

    float acc[8][8] = {};

    for (int kt = 0; kt < Kdim; kt += 16) {
        float4 a0 = *(const float4*)(aP0 + kt);
        float4 a1 = *(const float4*)(aP1 + kt);
        float4 b0 = *(const float4*)(bP0 + kt);
        float4 b1 = *(const float4*)(bP1 + kt);
        As[k4+0][m0] = a0.x; As[k4+1][m0] = a0.y; As[k4+2][m0] = a0.z; As[k4+3][m0] = a0.w;
        As[k4+0][m1] = a1.x; As[k4+1][m1] = a1.y; As[k4+2][m1] = a1.z; As[k4+3][m1] = a1.w;
        Bs[k4+0][m0] = b0.x; Bs[k4+1][m0] = b0.y; Bs[k4+2][m0] = b0.z; Bs[k4+3][m0] = b0.w;
        Bs[k4+0][m1] = b1.x; Bs[k4+1][m1] = b1.y; Bs[k4+2][m1] = b1.z; Bs[k4+3][m1] = b1.w;
        __syncthreads();

        #pragma unroll
        for (int kk = 0; kk < 16; ++kk) {
            float a8[8], b8[8];
            *(float4*)(a8)     = *(const float4*)&As[kk][ty*8];
            *(float4*)(a8 + 4) = *(const float4*)&As[kk][ty*8 + 4];
            *(float4*)(b8)     = *(const float4*)&Bs[kk][tx*8];
            *(float4*)(b8 + 4) = *(const float4*)&Bs[kk][tx*8 + 4];
            #pragma unroll
            for (int i = 0; i < 8; ++i)
                #pragma unroll
                for (int j = 0; j < 8; ++j)
                    acc[i][j] = fmaf(a8[i], b8[j], acc[i][j]);
        }
        __syncthreads();
    }

    float bvals[8];
    #pragma unroll
    for (int j = 0; j < 8; ++j) bvals[j] = bias[col0 + tx*8 + j];

    #pragma unroll
    for (int i = 0; i < 8; ++i) {
        int r = row0 + ty*8 + i;
        float g = 1.f, bb = 0.f;
        if (BN0) { int m = r % 300; g = bn_g[m]; bb = bn_b[m]; }
        float o[8];
        #pragma unroll
        for (int j = 0; j < 8; ++j) {
            float v = acc[i][j] + bvals[j];
            if (BN0) v = v * g + bb;
            o[j] = v;
        }
        float* cp = C + (size_t)r * Ndim + col0 + tx*8;
        *(float4*)(cp)     = *(float4*)(o);
        *(float4*)(cp + 4) = *(float4*)(o + 4);
    }
}

// ---------------------------------------------------------------------------
// alpha_g: sig[r*8+g] = sigmoid(dot(x_dot[r,:1536], fcg_w[g,:]) + fcg_b[g])
// 1 wave per row, 4 rows per wave, fcg_w staged in LDS (48 KB).
// ---------------------------------------------------------------------------
__global__ __launch_bounds__(256)
void alpha_sig_k(const float* __restrict__ xdot, const float* __restrict__ fcg_w,
                 const float* __restrict__ fcg_b, float* __restrict__ sig)
{
    __shared__ float W[GG * EE];   // 48 KB
    for (int i = threadIdx.x; i < GG * EE; i += 256) W[i] = fcg_w[i];
    __syncthreads();

    const int wave = threadIdx.x >> 6;
    const int lane = threadIdx.x & 63;

    for (int rr = 0; rr < 4; ++rr) {
        int row = blockIdx.x * 16 + wave * 4 + rr;
        const float* xr = xdot + (size_t)row * EE;
        float acc[GG] = {};
        for (int c = lane; c < EE; c += 64) {
            float xv = xr[c];
            #pragma unroll
            for (int g = 0; g < GG; ++g) acc[g] = fmaf(xv, W[g * EE + c], acc[g]);
        }
        float myval = 0.f;
        #pragma unroll
        for (int g = 0; g < GG; ++g) {
            float s = acc[g];
            #pragma unroll
            for (int o = 32; o; o >>= 1) s += __shfl_xor(s, o);
            if (lane == g) myval = s + fcg_b[g];
        }
        if (lane < GG) {
            sig[(size_t)row * GG + lane] = 1.f / (1.f + __expf(-myval));
        }
    }
}

// ---------------------------------------------------------------------------
// softmax over rows of 64 (in place) then * sigmoid gate. 1 wave per row.
// w is (153600, 64); sig flat index == row index.
// ---------------------------------------------------------------------------
__global__ __launch_bounds__(256)
void softmax_act_k(float* __restrict__ w, const float* __restrict__ sig)
{
    int row  = blockIdx.x * 4 + (threadIdx.x >> 6);
    int lane = threadIdx.x & 63;
    float v = w[(size_t)row * 64 + lane];
    float m = v;
    #pragma unroll
    for (int o = 32; o; o >>= 1) m = fmaxf(m, __shfl_xor(m, o));
    float e = __expf(v - m);
    float s = e;
    #pragma unroll
    for (int o = 32; o; o >>= 1) s += __shfl_xor(s, o);
    w[(size_t)row * 64 + lane] = (e / s) * sig[row];
}

// ---------------------------------------------------------------------------
// a[n,k] = sum_p act[n,p,k]    (p = 2400)
// ---------------------------------------------------------------------------
__global__ __launch_bounds__(256)
void asum_k(const float* __restrict__ act, float* __restrict__ a)
{
    int n = blockIdx.x;
    int k = threadIdx.x & 63, q = threadIdx.x >> 6;
    const float* base = act + (size_t)n * PP * 64;
    float s = 0.f;
    for (int p = q * 600; p < (q + 1) * 600; ++p) s += base[(size_t)p * 64 + k];
    __shared__ float part[4][64];
    part[q][k] = s;
    __syncthreads();
    if (threadIdx.x < 64)
        a[n * 64 + threadIdx.x] = part[0][threadIdx.x] + part[1][threadIdx.x]
                                + part[2][threadIdx.x] + part[3][threadIdx.x];
}

// ---------------------------------------------------------------------------
// vlad[n,d,k] = sum_p act[n,p,k]*x_tilde[n,p,d] - a[n,k]*cw2[d,k]
// x_tilde[n,p,d] = xdot[n, p>>3, (p&7)*192 + d]
// grid (3 d-tiles, 64 n); block 256; 64x64 tile; 4x4 per thread; P chunk 16.
// ---------------------------------------------------------------------------
__global__ __launch_bounds__(256)
void vlad_k(const float* __restrict__ act, const float* __restrict__ xdot,
            const float* __restrict__ a, const float* __restrict__ cw2,
            float* __restrict__ vlad)
{
    const int dt = blockIdx.x, n = blockIdx.y;
    const int d0 = dt * 64;
    __shared__ float As[16][64];
    __shared__ float Xs[16][64];
    const int tid = threadIdx.x;
    const int tx = tid & 15, ty = tid >> 4;
    const int kb = tx * 4, db = ty * 4;
    const float* actn = act + (size_t)n * PP * 64;
    const float* xn   = xdot + (size_t)n * MM * EE;
    float acc[4][4] = {};

    const int lpp = tid >> 4, lk4 = (tid & 15) << 2;
    for (int pc = 0; pc < PP; pc += 16) {
        int p = pc + lpp;
        float4 av = *(const float4*)(actn + (size_t)p * 64 + lk4);
        *(float4*)&As[lpp][lk4] = av;
        float4 xv = *(const float4*)(xn + (size_t)(p >> 3) * EE + (p & 7) * GS + d0 + lk4);
        *(float4*)&Xs[lpp][lk4] = xv;
        __syncthreads();
        #pragma unroll
        for (int q = 0; q < 16; ++q) {
            float4 a4 = *(const float4*)&As[q][kb];
            float4 x4 = *(const float4*)&Xs[q][db];
            float aa[4] = {a4.x, a4.y, a4.z, a4.w};
            float xx[4] = {x4.x, x4.y, x4.z, x4.w};
            #pragma unroll
            for (int i = 0; i < 4; ++i)
                #pragma unroll
                for (int j = 0; j < 4; ++j)
                    acc[i][j] = fmaf(xx[i], aa[j], acc[i][j]);
        }
        __syncthreads();
    }

    float av[4];
    #pragma unroll
    for (int j = 0; j < 4; ++j) av[j] = a[n * 64 + kb + j];
    #pragma unroll
    for (int i = 0; i < 4; ++i) {
        int dd = d0 + db + i;
        float o[4];
        #pragma unroll
        for (int j = 0; j < 4; ++j)
            o[j] = acc[i][j] - av[j] * cw2[dd * 64 + kb + j];
        *(float4*)(vlad + ((size_t)n * GS + dd) * 64 + kb) = *(float4*)o;
    }
}

// ---------------------------------------------------------------------------
// intra-norm over d (192) per (n,k), then *bn1_g + bn1_b, in place.
// ---------------------------------------------------------------------------
__global__ __launch_bounds__(256)
void norm_k(float* __restrict__ vlad, const float* __restrict__ bn1g,
            const float* __restrict__ bn1b)
{
    int n = blockIdx.x;
    float* v = vlad + (size_t)n * DESC;
    int k = threadIdx.x & 63, q = threadIdx.x >> 6;
    float s = 0.f;
    for (int d = q * 48; d < q * 48 + 48; ++d) s += fabsf(v[d * 64 + k]);
    __shared__ float part[4][64];
    __shared__ float inv[64];
    part[q][k] = s;
    __syncthreads();
    if (threadIdx.x < 64) {
        float t = part[0][threadIdx.x] + part[1][threadIdx.x]
                + part[2][threadIdx.x] + part[3][threadIdx.x];
        inv[threadIdx.x] = 1.f / fmaxf(t, 1e-12f);
    }
    __syncthreads();
    float g = bn1g[0], b = bn1b[0];
    for (int idx = threadIdx.x; idx < DESC; idx += 256) {
        v[idx] = v[idx] * inv[idx & 63] * g + b;
    }
}

// ---------------------------------------------------------------------------
// cls_fc split-K: part[ks, n, b] = sum_{k in chunk} vlad[n,k]*W[b,k]
// grid: 8 col-tiles(64) x 48 K-splits(256 each). 64x64 tile, 4x4/thread.
// ---------------------------------------------------------------------------
__global__ __launch_bounds__(256)
void fsplit_k(const float* __restrict__ vlad, const float* __restrict__ W,
              float* __restrict__ part)
{
    const int bcol0 = (blockIdx.x & 7) * 64;
    const int ks = blockIdx.x >> 3;
    const int kc0 = ks * 256;
    __shared__ float Vs[32][68];
    __shared__ float Ws[32][68];
    const int tid = threadIdx.x, tx = tid & 15, ty = tid >> 4;
    float acc[4][4] = {};

    for (int kc = kc0; kc < kc0 + 256; kc += 32) {
        #pragma unroll
        for (int it = 0; it < 2; ++it) {
            int sl = tid + it * 256;
            int rr = sl >> 3, k4 = (sl & 7) << 2;
            float4 v = *(const float4*)(vlad + (size_t)rr * DESC + kc + k4);
            Vs[k4+0][rr] = v.x; Vs[k4+1][rr] = v.y; Vs[k4+2][rr] = v.z; Vs[k4+3][rr] = v.w;
            float4 w = *(const float4*)(W + (size_t)(bcol0 + rr) * DESC + kc + k4);
            Ws[k4+0][rr] = w.x; Ws[k4+1][rr] = w.y; Ws[k4+2][rr] = w.z; Ws[k4+3][rr] = w.w;
        }
        __syncthreads();
        #pragma unroll
        for (int q = 0; q < 32; ++q) {
            float4 wv = *(const float4*)&Ws[q][tx*4];
            float4 vv = *(const float4*)&Vs[q][ty*4];
            float wa[4] = {wv.x, wv.y, wv.z, wv.w};
            float va[4] = {vv.x, vv.y, vv.z, vv.w};
            #pragma unroll
            for (int i = 0; i < 4; ++i)
                #pragma unroll
                for (int j = 0; j < 4; ++j)
                    acc[i][j] = fmaf(va[i], wa[j], acc[i][j]);
        }
        __syncthreads();
    }
    float* p = part + (size_t)ks * (NN * NB);
    #pragma unroll
    for (int i = 0; i < 4; ++i) {
        int n = ty * 4 + i;
        float4 o = {acc[i][0], acc[i][1], acc[i][2], acc[i][3]};
        *(float4*)(p + (size_t)n * NB + bcol0 + tx*4) = o;
    }
}

__global__ __launch_bounds__(256)
void freduce_k(const float* __restrict__ part, const float* __restrict__ bias,
               const float* __restrict__ bng, const float* __restrict__ bnb,
               float* __restrict__ f)
{
    int idx = blockIdx.x * 256 + threadIdx.x;  // 0..32767
    float s = 0.f;
    for (int ks = 0; ks < 48; ++ks) s += part[(size_t)ks * (NN * NB) + idx];
    int b = idx & (NB - 1);
    f[idx] = (s + bias[b]) * bng[b] + bnb[b];
}

// ---------------------------------------------------------------------------
// cls[n,c] = dot(f[n,:512], cls_w[c,:512]) + cls_b[c]; 64x64 tile, 4x4/thread.
// ---------------------------------------------------------------------------
__global__ __launch_bounds__(256)
void cls_k(const float* __restrict__ f, const float* __restrict__ W,
           const float* __restrict__ bias, float* __restrict__ out)
{
    const int c0 = blockIdx.x * 64;
    __shared__ float Fs[32][68];
    __shared__ float Ws[32][68];
    const int tid = threadIdx.x, tx = tid & 15, ty = tid >> 4;
    float acc[4][4] = {};

    for (int kc = 0; kc < NB; kc += 32) {
        #pragma unroll
        for (int it = 0; it < 2; ++it) {
            int sl = tid + it * 256;
            int rr = sl >> 3, k4 = (sl & 7) << 2;
            float4 v = *(const float4*)(f + (size_t)rr * NB + kc + k4);
            Fs[k4+0][rr] = v.x; Fs[k4+1][rr] = v.y; Fs[k4+2][rr] = v.z; Fs[k4+3][rr] = v.w;
            int c = c0 + rr;
            float4 w = (c < NCLS) ? *(const float4*)(W + (size_t)c * NB + kc + k4)
                                  : make_float4(0.f, 0.f, 0.f, 0.f);
            Ws[k4+0][rr] = w.x; Ws[k4+1][rr] = w.y; Ws[k4+2][rr] = w.z; Ws[k4+3][rr] = w.w;
        }
        __syncthreads();
        #pragma unroll
        for (int q = 0; q < 32; ++q) {
            float4 wv = *(const float4*)&Ws[q][tx*4];
            float4 fv = *(const float4*)&Fs[q][ty*4];
            float wa[4] = {wv.x, wv.y, wv.z, wv.w};
            float fa[4] = {fv.x, fv.y, fv.z, fv.w};
            #pragma unroll
            for (int i = 0; i < 4; ++i)
                #pragma unroll
                for (int j = 0; j < 4; ++j)
                    acc[i][j] = fmaf(fa[i], wa[j], acc[i][j]);
        }
        __syncthreads();
    }
    #pragma unroll
    for (int i = 0; i < 4; ++i) {
        int n = ty * 4 + i;
        #pragma unroll
        for (int j = 0; j < 4; ++j) {
            int c = c0 + tx * 4 + j;
            if (c < NCLS) out[(size_t)n * NCLS + c] = acc[i][j] + bias[c];
        }
    }
}

// ---------------------------------------------------------------------------
extern "C" void kernel_launch(void* const* d_in, const int* in_sizes, int n_in,
                              void* d_out, int out_size, void* d_ws, size_t ws_size,
                              hipStream_t stream)
{
    const float* features = (const float*)d_in[0];
    const float* fc0_w    = (const float*)d_in[1];
    const float* fc0_b    = (const float*)d_in[2];
    const float* fcgk_w   = (const float*)d_in[3];
    const float* fcgk_b   = (const float*)d_in[4];
    const float* fcg_w    = (const float*)d_in[5];
    const float* fcg_b    = (const float*)d_in[6];
    const float* bn0_g    = (const float*)d_in[7];
    const float* bn0_b    = (const float*)d_in[8];
    const float* cw2      = (const float*)d_in[9];
    const float* bn1_g    = (const float*)d_in[10];
    const float* bn1_b    = (const float*)d_in[11];
    const float* cls_fc_w = (const float*)d_in[12];
    const float* cls_fc_b = (const float*)d_in[13];
    const float* cls_bn_g = (const float*)d_in[14];
    const float* cls_bn_b = (const float*)d_in[15];
    const float* cls_w    = (const float*)d_in[16];
    const float* cls_b    = (const float*)d_in[17];

    // Workspace layout (floats). Total ~167.4M floats? No: 41,838,592 floats = 160 MB.
    float* ws    = (float*)d_ws;
    float* xdot  = ws;                       // 19200*1536   = 29,491,200
    float* wgkx  = ws + 29491200;            // 19200*512    =  9,830,400 (aliases activation)
    float* sigma = ws + 39321600;            // 19200*8      =    153,600
    float* asum  = ws + 39475200;            // 64*64        =      4,096
    float* vlad  = ws + 39479296;            // 64*12288     =    786,432
    float* fpart = ws + 40265728;            // 48*64*512    =  1,572,864  -> end 41,838,592

    float* cls_out = (float*)d_out;          // 64*701 = 44864
    float* f_out   = cls_out + NN * NCLS;    // 64*512 = 32768

    dim3 blk(256);

    // 1. x_dot = features[:,1:] @ fc0_w^T + fc0_b        (19200 x 1536, K=768)
    sgemm_nt<true, false><<<dim3(12, 150), blk, 0, stream>>>(
        features, CC, fc0_w, CC, fc0_b, nullptr, nullptr, xdot, EE, CC);

    // 2. WgkX = x_dot @ fcgk_w^T + fcgk_b, then bn0      (19200 x 512, K=1536)
    sgemm_nt<false, true><<<dim3(4, 150), blk, 0, stream>>>(
        xdot, EE, fcgk_w, EE, fcgk_b, bn0_g, bn0_b, wgkx, FF, EE);

    // 3. alpha_g = sigmoid(x_dot @ fcg_w^T + fcg_b)      (19200 x 8)
    alpha_sig_k<<<1200, blk, 0, stream>>>(xdot, fcg_w, fcg_b, sigma);

    // 4. activation = softmax(rows of 64) * gate  (in place on wgkx)
    softmax_act_k<<<38400, blk, 0, stream>>>(wgkx, sigma);

    // 5. a[n,k] = sum_p activation
    asum_k<<<64, blk, 0, stream>>>(wgkx, asum);

    // 6. vlad = act^T @ x_tilde - a*cw2                  (64 x 192 x 64)
    vlad_k<<<dim3(3, 64), blk, 0, stream>>>(wgkx, xdot, asum, cw2, vlad);

    // 7. intra-norm + bn1 (in place)
    norm_k<<<64, blk, 0, stream>>>(vlad, bn1_g, bn1_b);

    // 8. f = vlad @ cls_fc_w^T + b, *bn (split-K then reduce), write to d_out
    fsplit_k<<<384, blk, 0, stream>>>(vlad, cls_fc_w, fpart);
    freduce_k<<<128, blk, 0, stream>>>(fpart, cls_fc_b, cls_bn_g, cls_bn_b, f_out);

    // 9. cls = f @ cls_w^T + cls_b, write to d_out
    cls_k<<<11, blk, 0, stream>>>(f_out, cls_w, cls_b, cls_out);
}

// Round 2
// 599.382 us; speedup vs baseline: 2.3871x; 2.3871x over previous
//
#include <hip/hip_runtime.h>
#include <hip/hip_bf16.h>

// NeXtVLAD forward. Round 2: fp16 MFMA for the two big GEMMs (m97 structure),
// fp16 x_dot everywhere downstream; everything else fp32 as round 1.
#define NN 64
#define MM 300
#define CC 768
#define EE 1536          // LAMB*C
#define GG 8
#define KK 64
#define FF 512           // G*K
#define GS 192           // LAMB*C/G
#define PP 2400          // M*G
#define DESC 12288       // K*GS
#define NMROWS 19200     // N*M
#define NB 512
#define NCLS 701

typedef _Float16 v8h __attribute__((ext_vector_type(8)));
typedef _Float16 v4h __attribute__((ext_vector_type(4)));
typedef float    v4f __attribute__((ext_vector_type(4)));

#define GLOAD_LDS16(g, s) \
    __builtin_amdgcn_global_load_lds( \
        (const __attribute__((address_space(1))) void*)(g), \
        (__attribute__((address_space(3))) void*)(s), 16, 0, 0)

// ---------------------------------------------------------------------------
// pack features[:,1:] -> fp16, flattening the (n, 1+m) row skip.
// ---------------------------------------------------------------------------
__global__ __launch_bounds__(256)
void pack_x_k(const float* __restrict__ f, _Float16* __restrict__ o)
{
    int idx = blockIdx.x * 256 + threadIdx.x;     // 0 .. 19200*768/4 - 1
    int row = idx / 192;                          // 192 float4 per row
    int c4  = (idx - row * 192) * 4;
    int n = row / 300, m = row - n * 300;
    float4 v = *(const float4*)(f + ((size_t)(n * 301 + m + 1)) * CC + c4);
    v4h h = { (_Float16)v.x, (_Float16)v.y, (_Float16)v.z, (_Float16)v.w };
    *(v4h*)(o + (size_t)row * CC + c4) = h;
}

__global__ __launch_bounds__(256)
void pack_w_k(const float* __restrict__ s, _Float16* __restrict__ o, int n4)
{
    int idx = blockIdx.x * 256 + threadIdx.x;
    if (idx >= n4) return;
    float4 v = *(const float4*)(s + (size_t)idx * 4);
    v4h h = { (_Float16)v.x, (_Float16)v.y, (_Float16)v.z, (_Float16)v.w };
    *(v4h*)(o + (size_t)idx * 4) = h;
}

// ---------------------------------------------------------------------------
// MFMA fp16 GEMM:  C[i,j] = sum_k A[i,k]*B[j,k] + bias[j]  (both K-contig)
// 128x128 tile, BK=32, 256 thr = 4 waves (2x2 of 64x64), 4x4 16x16 MFMAs/wave.
// OUTF16: store _Float16 (x_dot). BN0: v=(v+bias)*bn_g[r%300]+bn_b[r%300], fp32.
// ---------------------------------------------------------------------------
template<bool OUTF16, bool BN0>
__global__ __launch_bounds__(256)
void hgemm_nt(const _Float16* __restrict__ A, const _Float16* __restrict__ B,
              const float* __restrict__ bias,
              const float* __restrict__ bn_g, const float* __restrict__ bn_b,
              void* __restrict__ Cout, int Ndim, int Kdim)
{
    __shared__ _Float16 As[128 * 32];   // row-major [row][32], 64 B/row
    __shared__ _Float16 Bs[128 * 32];

    const int tid  = threadIdx.x;
    const int wave = tid >> 6, lane = tid & 63;
    const int wr   = wave >> 1, wc = wave & 1;
    const int row0 = blockIdx.y * 128, col0 = blockIdx.x * 128;

    // staging: tile = 8 KB = 512 chunks of 16 B; 2 insts x 256 threads each
    // for A, same for B. chunk l -> row l>>2, half-offset (l&3)*8.
    const int l0 = tid, l1 = 256 + tid;
    const _Float16* ga0 = A + (size_t)(row0 + (l0 >> 2)) * Kdim + (l0 & 3) * 8;
    const _Float16* ga1 = A + (size_t)(row0 + (l1 >> 2)) * Kdim + (l1 & 3) * 8;
    const _Float16* gb0 = B + (size_t)(col0 + (l0 >> 2)) * Kdim + (l0 & 3) * 8;
    const _Float16* gb1 = B + (size_t)(col0 + (l1 >> 2)) * Kdim + (l1 & 3) * 8;
    // wave-uniform LDS bases; lane lands at base + lane*16 bytes.
    _Float16* sa0 = As + wave * 512;           // inst0: bytes [0,4096)
    _Float16* sa1 = As + 2048 + wave * 512;    // inst1: bytes [4096,8192)
    _Float16* sb0 = Bs + wave * 512;
    _Float16* sb1 = Bs + 2048 + wave * 512;

    v4f acc[4][4];
    #pragma unroll
    for (int i = 0; i < 4; ++i)
        #pragma unroll
        for (int j = 0; j < 4; ++j)
            acc[i][j] = (v4f){0.f, 0.f, 0.f, 0.f};

    const int fm = lane & 15, fq = lane >> 4;
    const _Float16* arp = As + (wr * 64 + fm) * 32 + fq * 8;
    const _Float16* brp = Bs + (wc * 64 + fm) * 32 + fq * 8;

    for (int kt = 0; kt < Kdim; kt += 32) {
        GLOAD_LDS16(ga0 + kt, sa0);
        GLOAD_LDS16(ga1 + kt, sa1);
        GLOAD_LDS16(gb0 + kt, sb0);
        GLOAD_LDS16(gb1 + kt, sb1);
        __syncthreads();   // vmcnt(0) drain + barrier: LDS tile ready

        v8h af[4], bf[4];
        #pragma unroll
        for (int i = 0; i < 4; ++i) af[i] = *(const v8h*)(arp + i * 16 * 32);
        #pragma unroll
        for (int j = 0; j < 4; ++j) bf[j] = *(const v8h*)(brp + j * 16 * 32);
        #pragma unroll
        for (int i = 0; i < 4; ++i)
            #pragma unroll
            for (int j = 0; j < 4; ++j)
                acc[i][j] = __builtin_amdgcn_mfma_f32_16x16x32_f16(
                    af[i], bf[j], acc[i][j], 0, 0, 0);
        __syncthreads();   // all ds_reads done before next stage overwrites
    }

    // epilogue: D col = lane&15 (B side), row = (lane>>4)*4 + reg (A side)
    float bj[4];
    #pragma unroll
    for (int j = 0; j < 4; ++j) bj[j] = bias[col0 + wc * 64 + j * 16 + fm];

    #pragma unroll
    for (int i = 0; i < 4; ++i) {
        #pragma unroll
        for (int r = 0; r < 4; ++r) {
            int grow = row0 + wr * 64 + i * 16 + fq * 4 + r;
            float g = 1.f, bb = 0.f;
            if (BN0) { int m = grow % 300; g = bn_g[m]; bb = bn_b[m]; }
            #pragma unroll
            for (int j = 0; j < 4; ++j) {
                int gcol = col0 + wc * 64 + j * 16 + fm;
                float v = acc[i][j][r] + bj[j];
                if (BN0) v = v * g + bb;
                if (OUTF16)
                    ((_Float16*)Cout)[(size_t)grow * Ndim + gcol] = (_Float16)v;
                else
                    ((float*)Cout)[(size_t)grow * Ndim + gcol] = v;
            }
        }
    }
}

// ---------------------------------------------------------------------------
// alpha_g: sig[r*8+g] = sigmoid(dot(x_dot[r,:1536], fcg_w[g,:]) + fcg_b[g])
// ---------------------------------------------------------------------------
__global__ __launch_bounds__(256)
void alpha_sig_k(const _Float16* __restrict__ xdot, const float* __restrict__ fcg_w,
                 const float* __restrict__ fcg_b, float* __restrict__ sig)
{
    __shared__ float W[GG * EE];   // 48 KB
    for (int i = threadIdx.x; i < GG * EE; i += 256) W[i] = fcg_w[i];
    __syncthreads();

    const int wave = threadIdx.x >> 6;
    const int lane = threadIdx.x & 63;

    for (int rr = 0; rr < 4; ++rr) {
        int row = blockIdx.x * 16 + wave * 4 + rr;
        const _Float16* xr = xdot + (size_t)row * EE;
        float acc[GG] = {};
        for (int c = lane; c < EE; c += 64) {
            float xv = (float)xr[c];
            #pragma unroll
            for (int g = 0; g < GG; ++g) acc[g] = fmaf(xv, W[g * EE + c], acc[g]);
        }
        float myval = 0.f;
        #pragma unroll
        for (int g = 0; g < GG; ++g) {
            float s = acc[g];
            #pragma unroll
            for (int o = 32; o; o >>= 1) s += __shfl_xor(s, o);
            if (lane == g) myval = s + fcg_b[g];
        }
        if (lane < GG) {
            sig[(size_t)row * GG + lane] = 1.f / (1.f + __expf(-myval));
        }
    }
}

// ---------------------------------------------------------------------------
// softmax over rows of 64 (in place) then * sigmoid gate. 1 wave per row.
// ---------------------------------------------------------------------------
__global__ __launch_bounds__(256)
void softmax_act_k(float* __restrict__ w, const float* __restrict__ sig)
{
    int row  = blockIdx.x * 4 + (threadIdx.x >> 6);
    int lane = threadIdx.x & 63;
    float v = w[(size_t)row * 64 + lane];
    float m = v;
    #pragma unroll
    for (int o = 32; o; o >>= 1) m = fmaxf(m, __shfl_xor(m, o));
    float e = __expf(v - m);
    float s = e;
    #pragma unroll
    for (int o = 32; o; o >>= 1) s += __shfl_xor(s, o);
    w[(size_t)row * 64 + lane] = (e / s) * sig[row];
}

// ---------------------------------------------------------------------------
// a[n,k] = sum_p act[n,p,k]
// ---------------------------------------------------------------------------
__global__ __launch_bounds__(256)
void asum_k(const float* __restrict__ act, float* __restrict__ a)
{
    int n = blockIdx.x;
    int k = threadIdx.x & 63, q = threadIdx.x >> 6;
    const float* base = act + (size_t)n * PP * 64;
    float s = 0.f;
    for (int p = q * 600; p < (q + 1) * 600; ++p) s += base[(size_t)p * 64 + k];
    __shared__ float part[4][64];
    part[q][k] = s;
    __syncthreads();
    if (threadIdx.x < 64)
        a[n * 64 + threadIdx.x] = part[0][threadIdx.x] + part[1][threadIdx.x]
                                + part[2][threadIdx.x] + part[3][threadIdx.x];
}

// ---------------------------------------------------------------------------
// vlad[n,d,k] = sum_p act[n,p,k]*x_tilde[n,p,d] - a[n,k]*cw2[d,k]
// x_tilde[n,p,d] = xdot16[n, p>>3, (p&7)*192 + d]
// ---------------------------------------------------------------------------
__global__ __launch_bounds__(256)
void vlad_k(const float* __restrict__ act, const _Float16* __restrict__ xdot,
            const float* __restrict__ a, const float* __restrict__ cw2,
            float* __restrict__ vlad)
{
    const int dt = blockIdx.x, n = blockIdx.y;
    const int d0 = dt * 64;
    __shared__ float As[16][64];
    __shared__ float Xs[16][64];
    const int tid = threadIdx.x;
    const int tx = tid & 15, ty = tid >> 4;
    const int kb = tx * 4, db = ty * 4;
    const float* actn = act + (size_t)n * PP * 64;
    const _Float16* xn = xdot + (size_t)n * MM * EE;
    float acc[4][4] = {};

    const int lpp = tid >> 4, lk4 = (tid & 15) << 2;
    for (int pc = 0; pc < PP; pc += 16) {
        int p = pc + lpp;
        float4 av = *(const float4*)(actn + (size_t)p * 64 + lk4);
        *(float4*)&As[lpp][lk4] = av;
        v4h xv = *(const v4h*)(xn + (size_t)(p >> 3) * EE + (p & 7) * GS + d0 + lk4);
        Xs[lpp][lk4 + 0] = (float)xv[0];
        Xs[lpp][lk4 + 1] = (float)xv[1];
        Xs[lpp][lk4 + 2] = (float)xv[2];
        Xs[lpp][lk4 + 3] = (float)xv[3];
        __syncthreads();
        #pragma unroll
        for (int q = 0; q < 16; ++q) {
            float4 a4 = *(const float4*)&As[q][kb];
            float4 x4 = *(const float4*)&Xs[q][db];
            float aa[4] = {a4.x, a4.y, a4.z, a4.w};
            float xx[4] = {x4.x, x4.y, x4.z, x4.w};
            #pragma unroll
            for (int i = 0; i < 4; ++i)
                #pragma unroll
                for (int j = 0; j < 4; ++j)
                    acc[i][j] = fmaf(xx[i], aa[j], acc[i][j]);
        }
        __syncthreads();
    }

    float av[4];
    #pragma unroll
    for (int j = 0; j < 4; ++j) av[j] = a[n * 64 + kb + j];
    #pragma unroll
    for (int i = 0; i < 4; ++i) {
        int dd = d0 + db + i;
        float o[4];
        #pragma unroll
        for (int j = 0; j < 4; ++j)
            o[j] = acc[i][j] - av[j] * cw2[dd * 64 + kb + j];
        *(float4*)(vlad + ((size_t)n * GS + dd) * 64 + kb) = *(float4*)o;
    }
}

// ---------------------------------------------------------------------------
// intra-norm over d (192) per (n,k), then *bn1_g + bn1_b, in place.
// ---------------------------------------------------------------------------
__global__ __launch_bounds__(256)
void norm_k(float* __restrict__ vlad, const float* __restrict__ bn1g,
            const float* __restrict__ bn1b)
{
    int n = blockIdx.x;
    float* v = vlad + (size_t)n * DESC;
    int k = threadIdx.x & 63, q = threadIdx.x >> 6;
    float s = 0.f;
    for (int d = q * 48; d < q * 48 + 48; ++d) s += fabsf(v[d * 64 + k]);
    __shared__ float part[4][64];
    __shared__ float inv[64];
    part[q][k] = s;
    __syncthreads();
    if (threadIdx.x < 64) {
        float t = part[0][threadIdx.x] + part[1][threadIdx.x]
                + part[2][threadIdx.x] + part[3][threadIdx.x];
        inv[threadIdx.x] = 1.f / fmaxf(t, 1e-12f);
    }
    __syncthreads();
    float g = bn1g[0], b = bn1b[0];
    for (int idx = threadIdx.x; idx < DESC; idx += 256) {
        v[idx] = v[idx] * inv[idx & 63] * g + b;
    }
}

// ---------------------------------------------------------------------------
// cls_fc split-K: part[ks, n, b] = sum_{k chunk} vlad[n,k]*W[b,k]
// ---------------------------------------------------------------------------
__global__ __launch_bounds__(256)
void fsplit_k(const float* __restrict__ vlad, const float* __restrict__ W,
              float* __restrict__ part)
{
    const int bcol0 = (blockIdx.x & 7) * 64;
    const int ks = blockIdx.x >> 3;
    const int kc0 = ks * 256;
    __shared__ float Vs[32][68];
    __shared__ float Ws[32][68];
    const int tid = threadIdx.x, tx = tid & 15, ty = tid >> 4;
    float acc[4][4] = {};

    for (int kc = kc0; kc < kc0 + 256; kc += 32) {
        #pragma unroll
        for (int it = 0; it < 2; ++it) {
            int sl = tid + it * 256;
            int rr = sl >> 3, k4 = (sl & 7) << 2;
            float4 v = *(const float4*)(vlad + (size_t)rr * DESC + kc + k4);
            Vs[k4+0][rr] = v.x; Vs[k4+1][rr] = v.y; Vs[k4+2][rr] = v.z; Vs[k4+3][rr] = v.w;
            float4 w = *(const float4*)(W + (size_t)(bcol0 + rr) * DESC + kc + k4);
            Ws[k4+0][rr] = w.x; Ws[k4+1][rr] = w.y; Ws[k4+2][rr] = w.z; Ws[k4+3][rr] = w.w;
        }
        __syncthreads();
        #pragma unroll
        for (int q = 0; q < 32; ++q) {
            float4 wv = *(const float4*)&Ws[q][tx*4];
            float4 vv = *(const float4*)&Vs[q][ty*4];
            float wa[4] = {wv.x, wv.y, wv.z, wv.w};
            float va[4] = {vv.x, vv.y, vv.z, vv.w};
            #pragma unroll
            for (int i = 0; i < 4; ++i)
                #pragma unroll
                for (int j = 0; j < 4; ++j)
                    acc[i][j] = fmaf(va[i], wa[j], acc[i][j]);
        }
        __syncthreads();
    }
    float* p = part + (size_t)ks * (NN * NB);
    #pragma unroll
    for (int i = 0; i < 4; ++i) {
        int n = ty * 4 + i;
        float4 o = {acc[i][0], acc[i][1], acc[i][2], acc[i][3]};
        *(float4*)(p + (size_t)n * NB + bcol0 + tx*4) = o;
    }
}

__global__ __launch_bounds__(256)
void freduce_k(const float* __restrict__ part, const float* __restrict__ bias,
               const float* __restrict__ bng, const float* __restrict__ bnb,
               float* __restrict__ f)
{
    int idx = blockIdx.x * 256 + threadIdx.x;  // 0..32767
    float s = 0.f;
    for (int ks = 0; ks < 48; ++ks) s += part[(size_t)ks * (NN * NB) + idx];
    int b = idx & (NB - 1);
    f[idx] = (s + bias[b]) * bng[b] + bnb[b];
}

// ---------------------------------------------------------------------------
// cls[n,c] = dot(f[n,:512], cls_w[c,:512]) + cls_b[c]
// ---------------------------------------------------------------------------
__global__ __launch_bounds__(256)
void cls_k(const float* __restrict__ f, const float* __restrict__ W,
           const float* __restrict__ bias, float* __restrict__ out)
{
    const int c0 = blockIdx.x * 64;
    __shared__ float Fs[32][68];
    __shared__ float Ws[32][68];
    const int tid = threadIdx.x, tx = tid & 15, ty = tid >> 4;
    float acc[4][4] = {};

    for (int kc = 0; kc < NB; kc += 32) {
        #pragma unroll
        for (int it = 0; it < 2; ++it) {
            int sl = tid + it * 256;
            int rr = sl >> 3, k4 = (sl & 7) << 2;
            float4 v = *(const float4*)(f + (size_t)rr * NB + kc + k4);
            Fs[k4+0][rr] = v.x; Fs[k4+1][rr] = v.y; Fs[k4+2][rr] = v.z; Fs[k4+3][rr] = v.w;
            int c = c0 + rr;
            float4 w = (c < NCLS) ? *(const float4*)(W + (size_t)c * NB + kc + k4)
                                  : make_float4(0.f, 0.f, 0.f, 0.f);
            Ws[k4+0][rr] = w.x; Ws[k4+1][rr] = w.y; Ws[k4+2][rr] = w.z; Ws[k4+3][rr] = w.w;
        }
        __syncthreads();
        #pragma unroll
        for (int q = 0; q < 32; ++q) {
            float4 wv = *(const float4*)&Ws[q][tx*4];
            float4 fv = *(const float4*)&Fs[q][ty*4];
            float wa[4] = {wv.x, wv.y, wv.z, wv.w};
            float fa[4] = {fv.x, fv.y, fv.z, fv.w};
            #pragma unroll
            for (int i = 0; i < 4; ++i)
                #pragma unroll
                for (int j = 0; j < 4; ++j)
                    acc[i][j] = fmaf(fa[i], wa[j], acc[i][j]);
        }
        __syncthreads();
    }
    #pragma unroll
    for (int i = 0; i < 4; ++i) {
        int n = ty * 4 + i;
        #pragma unroll
        for (int j = 0; j < 4; ++j) {
            int c = c0 + tx * 4 + j;
            if (c < NCLS) out[(size_t)n * NCLS + c] = acc[i][j] + bias[c];
        }
    }
}

// ---------------------------------------------------------------------------
extern "C" void kernel_launch(void* const* d_in, const int* in_sizes, int n_in,
                              void* d_out, int out_size, void* d_ws, size_t ws_size,
                              hipStream_t stream)
{
    const float* features = (const float*)d_in[0];
    const float* fc0_w    = (const float*)d_in[1];
    const float* fc0_b    = (const float*)d_in[2];
    const float* fcgk_w   = (const float*)d_in[3];
    const float* fcgk_b   = (const float*)d_in[4];
    const float* fcg_w    = (const float*)d_in[5];
    const float* fcg_b    = (const float*)d_in[6];
    const float* bn0_g    = (const float*)d_in[7];
    const float* bn0_b    = (const float*)d_in[8];
    const float* cw2      = (const float*)d_in[9];
    const float* bn1_g    = (const float*)d_in[10];
    const float* bn1_b    = (const float*)d_in[11];
    const float* cls_fc_w = (const float*)d_in[12];
    const float* cls_fc_b = (const float*)d_in[13];
    const float* cls_bn_g = (const float*)d_in[14];
    const float* cls_bn_b = (const float*)d_in[15];
    const float* cls_w    = (const float*)d_in[16];
    const float* cls_b    = (const float*)d_in[17];

    // Workspace layout (bytes, all 16-aligned). Total ~141.8 MB.
    char* ws = (char*)d_ws;
    _Float16* xf16   = (_Float16*)(ws + 0);           // 19200*768  h = 29,491,200 B
    _Float16* w1f16  = (_Float16*)(ws + 29491200);    // 1536*768   h =  2,359,296 B
    _Float16* w2f16  = (_Float16*)(ws + 31850496);    // 512*1536   h =  1,572,864 B
    _Float16* xdot16 = (_Float16*)(ws + 33423360);    // 19200*1536 h = 58,982,400 B
    float*    wgkx   = (float*)   (ws + 92405760);    // 19200*512  f = 39,321,600 B
    float*    sigma  = (float*)   (ws + 131727360);   // 19200*8    f =    614,400 B
    float*    asum   = (float*)   (ws + 132341760);   // 64*64      f =     16,384 B
    float*    vlad   = (float*)   (ws + 132358144);   // 64*12288   f =  3,145,728 B
    float*    fpart  = (float*)   (ws + 135503872);   // 48*64*512  f =  6,291,456 B

    float* cls_out = (float*)d_out;          // 64*701
    float* f_out   = cls_out + NN * NCLS;    // 64*512

    dim3 blk(256);

    // 0. fp32 -> fp16 packs
    pack_x_k<<<14400, blk, 0, stream>>>(features, xf16);
    pack_w_k<<<1152, blk, 0, stream>>>(fc0_w, w1f16, EE * CC / 4);
    pack_w_k<<<768, blk, 0, stream>>>(fcgk_w, w2f16, FF * EE / 4);

    // 1. x_dot = x @ fc0_w^T + fc0_b   (19200 x 1536, K=768) -> fp16
    hgemm_nt<true, false><<<dim3(12, 150), blk, 0, stream>>>(
        xf16, w1f16, fc0_b, nullptr, nullptr, xdot16, EE, CC);

    // 2. WgkX = x_dot @ fcgk_w^T + fcgk_b, bn0   (19200 x 512, K=1536) -> fp32
    hgemm_nt<false, true><<<dim3(4, 150), blk, 0, stream>>>(
        xdot16, w2f16, fcgk_b, bn0_g, bn0_b, wgkx, FF, EE);

    // 3. alpha_g = sigmoid(x_dot @ fcg_w^T + fcg_b)
    alpha_sig_k<<<1200, blk, 0, stream>>>(xdot16, fcg_w, fcg_b, sigma);

    // 4. activation = softmax(rows of 64) * gate  (in place)
    softmax_act_k<<<38400, blk, 0, stream>>>(wgkx, sigma);

    // 5. a[n,k] = sum_p activation
    asum_k<<<64, blk, 0, stream>>>(wgkx, asum);

    // 6. vlad = act^T @ x_tilde - a*cw2
    vlad_k<<<dim3(3, 64), blk, 0, stream>>>(wgkx, xdot16, asum, cw2, vlad);

    // 7. intra-norm + bn1
    norm_k<<<64, blk, 0, stream>>>(vlad, bn1_g, bn1_b);

    // 8. f = vlad @ cls_fc_w^T (+bias)*bn
    fsplit_k<<<384, blk, 0, stream>>>(vlad, cls_fc_w, fpart);
    freduce_k<<<128, blk, 0, stream>>>(fpart, cls_fc_b, cls_bn_g, cls_bn_b, f_out);

    // 9. cls = f @ cls_w^T + cls_b
    cls_k<<<11, blk, 0, stream>>>(f_out, cls_w, cls_b, cls_out);
}

// Round 3
// 519.845 us; speedup vs baseline: 2.7523x; 1.1530x over previous
//
#include <hip/hip_runtime.h>
#include <hip/hip_bf16.h>

// NeXtVLAD forward. Round 3: split-P vlad (8-way) + softmax*gate fused into
// GEMM2 epilogue. fp16 MFMA GEMMs as round 2.
#define NN 64
#define MM 300
#define CC 768
#define EE 1536          // LAMB*C
#define GG 8
#define KK 64
#define FF 512           // G*K
#define GS 192           // LAMB*C/G
#define PP 2400          // M*G
#define DESC 12288       // K*GS
#define NMROWS 19200     // N*M
#define NB 512
#define NCLS 701

typedef _Float16 v8h __attribute__((ext_vector_type(8)));
typedef _Float16 v4h __attribute__((ext_vector_type(4)));
typedef float    v4f __attribute__((ext_vector_type(4)));

#define GLOAD_LDS16(g, s) \
    __builtin_amdgcn_global_load_lds( \
        (const __attribute__((address_space(1))) void*)(g), \
        (__attribute__((address_space(3))) void*)(s), 16, 0, 0)

// ---------------------------------------------------------------------------
// pack features[:,1:] -> fp16, flattening the (n, 1+m) row skip.
// ---------------------------------------------------------------------------
__global__ __launch_bounds__(256)
void pack_x_k(const float* __restrict__ f, _Float16* __restrict__ o)
{
    int idx = blockIdx.x * 256 + threadIdx.x;     // 0 .. 19200*768/4 - 1
    int row = idx / 192;                          // 192 float4 per row
    int c4  = (idx - row * 192) * 4;
    int n = row / 300, m = row - n * 300;
    float4 v = *(const float4*)(f + ((size_t)(n * 301 + m + 1)) * CC + c4);
    v4h h = { (_Float16)v.x, (_Float16)v.y, (_Float16)v.z, (_Float16)v.w };
    *(v4h*)(o + (size_t)row * CC + c4) = h;
}

__global__ __launch_bounds__(256)
void pack_w_k(const float* __restrict__ s, _Float16* __restrict__ o, int n4)
{
    int idx = blockIdx.x * 256 + threadIdx.x;
    if (idx >= n4) return;
    float4 v = *(const float4*)(s + (size_t)idx * 4);
    v4h h = { (_Float16)v.x, (_Float16)v.y, (_Float16)v.z, (_Float16)v.w };
    *(v4h*)(o + (size_t)idx * 4) = h;
}

// ---------------------------------------------------------------------------
// MFMA fp16 GEMM:  C[i,j] = sum_k A[i,k]*B[j,k] + bias[j]  (both K-contig)
// 128x128 tile, BK=32, 256 thr = 4 waves (2x2 of 64x64), 4x4 16x16 MFMAs/wave.
// OUTF16: store _Float16. BN0: v=(v+bias)*bn_g[r%300]+bn_b[r%300].
// SOFTGATE (implies BN0 path usage): per-row softmax over this wave's 64-col
// group (one g), times sigmoid gate sig[(n*300+m)*8+g]; fp32 out.
// ---------------------------------------------------------------------------
template<bool OUTF16, bool BN0, bool SOFTGATE>
__global__ __launch_bounds__(256)
void hgemm_nt(const _Float16* __restrict__ A, const _Float16* __restrict__ B,
              const float* __restrict__ bias,
              const float* __restrict__ bn_g, const float* __restrict__ bn_b,
              const float* __restrict__ sig,
              void* __restrict__ Cout, int Ndim, int Kdim)
{
    __shared__ _Float16 As[128 * 32];   // row-major [row][32], 64 B/row
    __shared__ _Float16 Bs[128 * 32];

    const int tid  = threadIdx.x;
    const int wave = tid >> 6, lane = tid & 63;
    const int wr   = wave >> 1, wc = wave & 1;
    const int row0 = blockIdx.y * 128, col0 = blockIdx.x * 128;

    const int l0 = tid, l1 = 256 + tid;
    const _Float16* ga0 = A + (size_t)(row0 + (l0 >> 2)) * Kdim + (l0 & 3) * 8;
    const _Float16* ga1 = A + (size_t)(row0 + (l1 >> 2)) * Kdim + (l1 & 3) * 8;
    const _Float16* gb0 = B + (size_t)(col0 + (l0 >> 2)) * Kdim + (l0 & 3) * 8;
    const _Float16* gb1 = B + (size_t)(col0 + (l1 >> 2)) * Kdim + (l1 & 3) * 8;
    _Float16* sa0 = As + wave * 512;
    _Float16* sa1 = As + 2048 + wave * 512;
    _Float16* sb0 = Bs + wave * 512;
    _Float16* sb1 = Bs + 2048 + wave * 512;

    v4f acc[4][4];
    #pragma unroll
    for (int i = 0; i < 4; ++i)
        #pragma unroll
        for (int j = 0; j < 4; ++j)
            acc[i][j] = (v4f){0.f, 0.f, 0.f, 0.f};

    const int fm = lane & 15, fq = lane >> 4;
    const _Float16* arp = As + (wr * 64 + fm) * 32 + fq * 8;
    const _Float16* brp = Bs + (wc * 64 + fm) * 32 + fq * 8;

    for (int kt = 0; kt < Kdim; kt += 32) {
        GLOAD_LDS16(ga0 + kt, sa0);
        GLOAD_LDS16(ga1 + kt, sa1);
        GLOAD_LDS16(gb0 + kt, sb0);
        GLOAD_LDS16(gb1 + kt, sb1);
        __syncthreads();

        v8h af[4], bf[4];
        #pragma unroll
        for (int i = 0; i < 4; ++i) af[i] = *(const v8h*)(arp + i * 16 * 32);
        #pragma unroll
        for (int j = 0; j < 4; ++j) bf[j] = *(const v8h*)(brp + j * 16 * 32);
        #pragma unroll
        for (int i = 0; i < 4; ++i)
            #pragma unroll
            for (int j = 0; j < 4; ++j)
                acc[i][j] = __builtin_amdgcn_mfma_f32_16x16x32_f16(
                    af[i], bf[j], acc[i][j], 0, 0, 0);
        __syncthreads();
    }

    // epilogue: D col = lane&15 + j*16 (B side), row = fq*4 + r + i*16 (A side)
    float bj[4];
    #pragma unroll
    for (int j = 0; j < 4; ++j) bj[j] = bias[col0 + wc * 64 + j * 16 + fm];

    if (SOFTGATE) {
        const int gidx = (col0 >> 6) + wc;     // softmax group of this wave
        #pragma unroll
        for (int i = 0; i < 4; ++i) {
            #pragma unroll
            for (int r = 0; r < 4; ++r) {
                int grow = row0 + wr * 64 + i * 16 + fq * 4 + r;
                int n = grow / 300, mm = grow - n * 300;
                float g = bn_g[mm], bb = bn_b[mm];
                float v[4];
                #pragma unroll
                for (int j = 0; j < 4; ++j)
                    v[j] = (acc[i][j][r] + bj[j]) * g + bb;
                float mx = fmaxf(fmaxf(v[0], v[1]), fmaxf(v[2], v[3]));
                #pragma unroll
                for (int w = 1; w < 16; w <<= 1) mx = fmaxf(mx, __shfl_xor(mx, w));
                float e[4], s = 0.f;
                #pragma unroll
                for (int j = 0; j < 4; ++j) { e[j] = __expf(v[j] - mx); s += e[j]; }
                #pragma unroll
                for (int w = 1; w < 16; w <<= 1) s += __shfl_xor(s, w);
                float gate = sig[(size_t)grow * GG + gidx];
                float inv = gate / s;
                float* cp = (float*)Cout + (size_t)grow * Ndim + col0 + wc * 64;
                #pragma unroll
                for (int j = 0; j < 4; ++j) cp[j * 16 + fm] = e[j] * inv;
            }
        }
        return;
    }

    #pragma unroll
    for (int i = 0; i < 4; ++i) {
        #pragma unroll
        for (int r = 0; r < 4; ++r) {
            int grow = row0 + wr * 64 + i * 16 + fq * 4 + r;
            float g = 1.f, bb = 0.f;
            if (BN0) { int m = grow % 300; g = bn_g[m]; bb = bn_b[m]; }
            #pragma unroll
            for (int j = 0; j < 4; ++j) {
                int gcol = col0 + wc * 64 + j * 16 + fm;
                float v = acc[i][j][r] + bj[j];
                if (BN0) v = v * g + bb;
                if (OUTF16)
                    ((_Float16*)Cout)[(size_t)grow * Ndim + gcol] = (_Float16)v;
                else
                    ((float*)Cout)[(size_t)grow * Ndim + gcol] = v;
            }
        }
    }
}

// ---------------------------------------------------------------------------
// alpha_g: sig[r*8+g] = sigmoid(dot(x_dot[r,:1536], fcg_w[g,:]) + fcg_b[g])
// ---------------------------------------------------------------------------
__global__ __launch_bounds__(256)
void alpha_sig_k(const _Float16* __restrict__ xdot, const float* __restrict__ fcg_w,
                 const float* __restrict__ fcg_b, float* __restrict__ sig)
{
    __shared__ float W[GG * EE];   // 48 KB
    for (int i = threadIdx.x; i < GG * EE; i += 256) W[i] = fcg_w[i];
    __syncthreads();

    const int wave = threadIdx.x >> 6;
    const int lane = threadIdx.x & 63;

    for (int rr = 0; rr < 4; ++rr) {
        int row = blockIdx.x * 16 + wave * 4 + rr;
        const _Float16* xr = xdot + (size_t)row * EE;
        float acc[GG] = {};
        for (int c = lane; c < EE; c += 64) {
            float xv = (float)xr[c];
            #pragma unroll
            for (int g = 0; g < GG; ++g) acc[g] = fmaf(xv, W[g * EE + c], acc[g]);
        }
        float myval = 0.f;
        #pragma unroll
        for (int g = 0; g < GG; ++g) {
            float s = acc[g];
            #pragma unroll
            for (int o = 32; o; o >>= 1) s += __shfl_xor(s, o);
            if (lane == g) myval = s + fcg_b[g];
        }
        if (lane < GG) {
            sig[(size_t)row * GG + lane] = 1.f / (1.f + __expf(-myval));
        }
    }
}

// ---------------------------------------------------------------------------
// a[n,k] = sum_p act[n,p,k]
// ---------------------------------------------------------------------------
__global__ __launch_bounds__(256)
void asum_k(const float* __restrict__ act, float* __restrict__ a)
{
    int n = blockIdx.x;
    int k = threadIdx.x & 63, q = threadIdx.x >> 6;
    const float* base = act + (size_t)n * PP * 64;
    float s = 0.f;
    for (int p = q * 600; p < (q + 1) * 600; ++p) s += base[(size_t)p * 64 + k];
    __shared__ float part[4][64];
    part[q][k] = s;
    __syncthreads();
    if (threadIdx.x < 64)
        a[n * 64 + threadIdx.x] = part[0][threadIdx.x] + part[1][threadIdx.x]
                                + part[2][threadIdx.x] + part[3][threadIdx.x];
}

// ---------------------------------------------------------------------------
// vlad partial, split over P 8 ways:
// part[ps,n,d,k] = sum_{p in [ps*300,ps*300+300)} act[n,p,k]*x_tilde[n,p,d]
// x_tilde[n,p,d] = xdot16[n, p>>3, (p&7)*192 + d]
// grid (3 d-tiles, 64 n, 8 ps); 64x64 tile; 4x4/thread; P chunk 16 (+guard).
// ---------------------------------------------------------------------------
__global__ __launch_bounds__(256)
void vlad_ps_k(const float* __restrict__ act, const _Float16* __restrict__ xdot,
               float* __restrict__ part)
{
    const int dt = blockIdx.x, n = blockIdx.y, ps = blockIdx.z;
    const int d0 = dt * 64;
    const int p0 = ps * 300, pend = p0 + 300;
    __shared__ float As[16][64];
    __shared__ float Xs[16][64];
    const int tid = threadIdx.x;
    const int tx = tid & 15, ty = tid >> 4;
    const int kb = tx * 4, db = ty * 4;
    const float* actn = act + (size_t)n * PP * 64;
    const _Float16* xn = xdot + (size_t)n * MM * EE;
    float acc[4][4] = {};

    const int lpp = tid >> 4, lk4 = (tid & 15) << 2;
    for (int pc = p0; pc < pend; pc += 16) {
        int p = pc + lpp;
        float4 av = make_float4(0.f, 0.f, 0.f, 0.f);
        float x0 = 0.f, x1 = 0.f, x2 = 0.f, x3 = 0.f;
        if (p < pend) {
            av = *(const float4*)(actn + (size_t)p * 64 + lk4);
            v4h xv = *(const v4h*)(xn + (size_t)(p >> 3) * EE + (p & 7) * GS + d0 + lk4);
            x0 = (float)xv[0]; x1 = (float)xv[1]; x2 = (float)xv[2]; x3 = (float)xv[3];
        }
        *(float4*)&As[lpp][lk4] = av;
        Xs[lpp][lk4 + 0] = x0; Xs[lpp][lk4 + 1] = x1;
        Xs[lpp][lk4 + 2] = x2; Xs[lpp][lk4 + 3] = x3;
        __syncthreads();
        #pragma unroll
        for (int q = 0; q < 16; ++q) {
            float4 a4 = *(const float4*)&As[q][kb];
            float4 x4 = *(const float4*)&Xs[q][db];
            float aa[4] = {a4.x, a4.y, a4.z, a4.w};
            float xx[4] = {x4.x, x4.y, x4.z, x4.w};
            #pragma unroll
            for (int i = 0; i < 4; ++i)
                #pragma unroll
                for (int j = 0; j < 4; ++j)
                    acc[i][j] = fmaf(xx[i], aa[j], acc[i][j]);
        }
        __syncthreads();
    }

    float* pp = part + ((size_t)ps * NN + n) * DESC;
    #pragma unroll
    for (int i = 0; i < 4; ++i) {
        int dd = d0 + db + i;
        float4 o = {acc[i][0], acc[i][1], acc[i][2], acc[i][3]};
        *(float4*)(pp + (size_t)dd * 64 + kb) = o;
    }
}

// ---------------------------------------------------------------------------
// vlad[n,d,k] = sum_ps part[ps,n,d,k] - a[n,k]*cw2[d,k]
// ---------------------------------------------------------------------------
__global__ __launch_bounds__(256)
void vlad_reduce_k(const float* __restrict__ part, const float* __restrict__ a,
                   const float* __restrict__ cw2, float* __restrict__ vlad)
{
    int idx = blockIdx.x * 256 + threadIdx.x;   // 0..786431 = (n*192+d)*64+k
    float s = 0.f;
    #pragma unroll
    for (int ps = 0; ps < 8; ++ps) s += part[(size_t)ps * (NN * DESC) + idx];
    int k = idx & 63;
    int d = (idx >> 6) % GS;
    int n = idx / DESC;
    vlad[idx] = s - a[n * 64 + k] * cw2[d * 64 + k];
}

// ---------------------------------------------------------------------------
// intra-norm over d (192) per (n,k), then *bn1_g + bn1_b, in place.
// ---------------------------------------------------------------------------
__global__ __launch_bounds__(256)
void norm_k(float* __restrict__ vlad, const float* __restrict__ bn1g,
            const float* __restrict__ bn1b)
{
    int n = blockIdx.x;
    float* v = vlad + (size_t)n * DESC;
    int k = threadIdx.x & 63, q = threadIdx.x >> 6;
    float s = 0.f;
    for (int d = q * 48; d < q * 48 + 48; ++d) s += fabsf(v[d * 64 + k]);
    __shared__ float part[4][64];
    __shared__ float inv[64];
    part[q][k] = s;
    __syncthreads();
    if (threadIdx.x < 64) {
        float t = part[0][threadIdx.x] + part[1][threadIdx.x]
                + part[2][threadIdx.x] + part[3][threadIdx.x];
        inv[threadIdx.x] = 1.f / fmaxf(t, 1e-12f);
    }
    __syncthreads();
    float g = bn1g[0], b = bn1b[0];
    for (int idx = threadIdx.x; idx < DESC; idx += 256) {
        v[idx] = v[idx] * inv[idx & 63] * g + b;
    }
}

// ---------------------------------------------------------------------------
// cls_fc split-K: part[ks, n, b] = sum_{k chunk} vlad[n,k]*W[b,k]
// ---------------------------------------------------------------------------
__global__ __launch_bounds__(256)
void fsplit_k(const float* __restrict__ vlad, const float* __restrict__ W,
              float* __restrict__ part)
{
    const int bcol0 = (blockIdx.x & 7) * 64;
    const int ks = blockIdx.x >> 3;
    const int kc0 = ks * 256;
    __shared__ float Vs[32][68];
    __shared__ float Ws[32][68];
    const int tid = threadIdx.x, tx = tid & 15, ty = tid >> 4;
    float acc[4][4] = {};

    for (int kc = kc0; kc < kc0 + 256; kc += 32) {
        #pragma unroll
        for (int it = 0; it < 2; ++it) {
            int sl = tid + it * 256;
            int rr = sl >> 3, k4 = (sl & 7) << 2;
            float4 v = *(const float4*)(vlad + (size_t)rr * DESC + kc + k4);
            Vs[k4+0][rr] = v.x; Vs[k4+1][rr] = v.y; Vs[k4+2][rr] = v.z; Vs[k4+3][rr] = v.w;
            float4 w = *(const float4*)(W + (size_t)(bcol0 + rr) * DESC + kc + k4);
            Ws[k4+0][rr] = w.x; Ws[k4+1][rr] = w.y; Ws[k4+2][rr] = w.z; Ws[k4+3][rr] = w.w;
        }
        __syncthreads();
        #pragma unroll
        for (int q = 0; q < 32; ++q) {
            float4 wv = *(const float4*)&Ws[q][tx*4];
            float4 vv = *(const float4*)&Vs[q][ty*4];
            float wa[4] = {wv.x, wv.y, wv.z, wv.w};
            float va[4] = {vv.x, vv.y, vv.z, vv.w};
            #pragma unroll
            for (int i = 0; i < 4; ++i)
                #pragma unroll
                for (int j = 0; j < 4; ++j)
                    acc[i][j] = fmaf(va[i], wa[j], acc[i][j]);
        }
        __syncthreads();
    }
    float* p = part + (size_t)ks * (NN * NB);
    #pragma unroll
    for (int i = 0; i < 4; ++i) {
        int n = ty * 4 + i;
        float4 o = {acc[i][0], acc[i][1], acc[i][2], acc[i][3]};
        *(float4*)(p + (size_t)n * NB + bcol0 + tx*4) = o;
    }
}

__global__ __launch_bounds__(256)
void freduce_k(const float* __restrict__ part, const float* __restrict__ bias,
               const float* __restrict__ bng, const float* __restrict__ bnb,
               float* __restrict__ f)
{
    int idx = blockIdx.x * 256 + threadIdx.x;  // 0..32767
    float s = 0.f;
    for (int ks = 0; ks < 48; ++ks) s += part[(size_t)ks * (NN * NB) + idx];
    int b = idx & (NB - 1);
    f[idx] = (s + bias[b]) * bng[b] + bnb[b];
}

// ---------------------------------------------------------------------------
// cls[n,c] = dot(f[n,:512], cls_w[c,:512]) + cls_b[c]
// ---------------------------------------------------------------------------
__global__ __launch_bounds__(256)
void cls_k(const float* __restrict__ f, const float* __restrict__ W,
           const float* __restrict__ bias, float* __restrict__ out)
{
    const int c0 = blockIdx.x * 64;
    __shared__ float Fs[32][68];
    __shared__ float Ws[32][68];
    const int tid = threadIdx.x, tx = tid & 15, ty = tid >> 4;
    float acc[4][4] = {};

    for (int kc = 0; kc < NB; kc += 32) {
        #pragma unroll
        for (int it = 0; it < 2; ++it) {
            int sl = tid + it * 256;
            int rr = sl >> 3, k4 = (sl & 7) << 2;
            float4 v = *(const float4*)(f + (size_t)rr * NB + kc + k4);
            Fs[k4+0][rr] = v.x; Fs[k4+1][rr] = v.y; Fs[k4+2][rr] = v.z; Fs[k4+3][rr] = v.w;
            int c = c0 + rr;
            float4 w = (c < NCLS) ? *(const float4*)(W + (size_t)c * NB + kc + k4)
                                  : make_float4(0.f, 0.f, 0.f, 0.f);
            Ws[k4+0][rr] = w.x; Ws[k4+1][rr] = w.y; Ws[k4+2][rr] = w.z; Ws[k4+3][rr] = w.w;
        }
        __syncthreads();
        #pragma unroll
        for (int q = 0; q < 32; ++q) {
            float4 wv = *(const float4*)&Ws[q][tx*4];
            float4 fv = *(const float4*)&Fs[q][ty*4];
            float wa[4] = {wv.x, wv.y, wv.z, wv.w};
            float fa[4] = {fv.x, fv.y, fv.z, fv.w};
            #pragma unroll
            for (int i = 0; i < 4; ++i)
                #pragma unroll
                for (int j = 0; j < 4; ++j)
                    acc[i][j] = fmaf(fa[i], wa[j], acc[i][j]);
        }
        __syncthreads();
    }
    #pragma unroll
    for (int i = 0; i < 4; ++i) {
        int n = ty * 4 + i;
        #pragma unroll
        for (int j = 0; j < 4; ++j) {
            int c = c0 + tx * 4 + j;
            if (c < NCLS) out[(size_t)n * NCLS + c] = acc[i][j] + bias[c];
        }
    }
}

// ---------------------------------------------------------------------------
extern "C" void kernel_launch(void* const* d_in, const int* in_sizes, int n_in,
                              void* d_out, int out_size, void* d_ws, size_t ws_size,
                              hipStream_t stream)
{
    const float* features = (const float*)d_in[0];
    const float* fc0_w    = (const float*)d_in[1];
    const float* fc0_b    = (const float*)d_in[2];
    const float* fcgk_w   = (const float*)d_in[3];
    const float* fcgk_b   = (const float*)d_in[4];
    const float* fcg_w    = (const float*)d_in[5];
    const float* fcg_b    = (const float*)d_in[6];
    const float* bn0_g    = (const float*)d_in[7];
    const float* bn0_b    = (const float*)d_in[8];
    const float* cw2      = (const float*)d_in[9];
    const float* bn1_g    = (const float*)d_in[10];
    const float* bn1_b    = (const float*)d_in[11];
    const float* cls_fc_w = (const float*)d_in[12];
    const float* cls_fc_b = (const float*)d_in[13];
    const float* cls_bn_g = (const float*)d_in[14];
    const float* cls_bn_b = (const float*)d_in[15];
    const float* cls_w    = (const float*)d_in[16];
    const float* cls_b    = (const float*)d_in[17];

    // Workspace layout (bytes, 16-aligned). Total ~159.2 MB.
    char* ws = (char*)d_ws;
    _Float16* xf16   = (_Float16*)(ws + 0);           // 29,491,200 B
    _Float16* w1f16  = (_Float16*)(ws + 29491200);    //  2,359,296 B
    _Float16* w2f16  = (_Float16*)(ws + 31850496);    //  1,572,864 B
    _Float16* xdot16 = (_Float16*)(ws + 33423360);    // 58,982,400 B
    float*    act    = (float*)   (ws + 92405760);    // 39,321,600 B (WgkX->activation)
    float*    sigma  = (float*)   (ws + 131727360);   //    614,400 B
    float*    asum   = (float*)   (ws + 132341760);   //     16,384 B
    float*    vlad   = (float*)   (ws + 132358144);   //  3,145,728 B
    float*    vpart  = (float*)   (ws + 135503872);   // 25,165,824 B (8x64x192x64)
    float*    fpart  = (float*)   (ws + 160669696);   //  6,291,456 B -> 166,961,152

    float* cls_out = (float*)d_out;          // 64*701
    float* f_out   = cls_out + NN * NCLS;    // 64*512

    dim3 blk(256);

    // 0. fp32 -> fp16 packs
    pack_x_k<<<14400, blk, 0, stream>>>(features, xf16);
    pack_w_k<<<1152, blk, 0, stream>>>(fc0_w, w1f16, EE * CC / 4);
    pack_w_k<<<768, blk, 0, stream>>>(fcgk_w, w2f16, FF * EE / 4);

    // 1. x_dot = x @ fc0_w^T + fc0_b   (19200 x 1536, K=768) -> fp16
    hgemm_nt<true, false, false><<<dim3(12, 150), blk, 0, stream>>>(
        xf16, w1f16, fc0_b, nullptr, nullptr, nullptr, xdot16, EE, CC);

    // 2. alpha_g = sigmoid(x_dot @ fcg_w^T + fcg_b)  (before GEMM2: gate input)
    alpha_sig_k<<<1200, blk, 0, stream>>>(xdot16, fcg_w, fcg_b, sigma);

    // 3. act = softmax((x_dot @ fcgk_w^T + b)*bn0) * gate   (fused epilogue)
    hgemm_nt<false, true, true><<<dim3(4, 150), blk, 0, stream>>>(
        xdot16, w2f16, fcgk_b, bn0_g, bn0_b, sigma, act, FF, EE);

    // 4. a[n,k] = sum_p act
    asum_k<<<64, blk, 0, stream>>>(act, asum);

    // 5. vlad partials (split-P x8) + reduce with -a*cw2
    vlad_ps_k<<<dim3(3, 64, 8), blk, 0, stream>>>(act, xdot16, vpart);
    vlad_reduce_k<<<3072, blk, 0, stream>>>(vpart, asum, cw2, vlad);

    // 6. intra-norm + bn1
    norm_k<<<64, blk, 0, stream>>>(vlad, bn1_g, bn1_b);

    // 7. f = vlad @ cls_fc_w^T (+bias)*bn
    fsplit_k<<<384, blk, 0, stream>>>(vlad, cls_fc_w, fpart);
    freduce_k<<<128, blk, 0, stream>>>(fpart, cls_fc_b, cls_bn_g, cls_bn_b, f_out);

    // 8. cls = f @ cls_w^T + cls_b
    cls_k<<<11, blk, 0, stream>>>(f_out, cls_w, cls_b, cls_out);
}

// Round 4
// 510.709 us; speedup vs baseline: 2.8016x; 1.0179x over previous
//
#include <hip/hip_runtime.h>
#include <hip/hip_bf16.h>

// NeXtVLAD forward. Round 4: composed weights (W2@W1, fcg@W1) halve GEMM2's K
// and decouple it from x_dot; XOR-swizzled LDS in hgemm (kills 8-way fragment
// bank conflicts); act stored fp16; asum split 8-way over p.
#define NN 64
#define MM 300
#define CC 768
#define EE 1536          // LAMB*C
#define GG 8
#define KK 64
#define FF 512           // G*K
#define GS 192           // LAMB*C/G
#define PP 2400          // M*G
#define DESC 12288       // K*GS
#define NMROWS 19200     // N*M
#define NB 512
#define NCLS 701

typedef _Float16 v8h __attribute__((ext_vector_type(8)));
typedef _Float16 v4h __attribute__((ext_vector_type(4)));
typedef float    v4f __attribute__((ext_vector_type(4)));

#define GLOAD_LDS16(g, s) \
    __builtin_amdgcn_global_load_lds( \
        (const __attribute__((address_space(1))) void*)(g), \
        (__attribute__((address_space(3))) void*)(s), 16, 0, 0)

// ---------------------------------------------------------------------------
// pack features[:,1:] -> fp16, flattening the (n, 1+m) row skip.
// ---------------------------------------------------------------------------
__global__ __launch_bounds__(256)
void pack_x_k(const float* __restrict__ f, _Float16* __restrict__ o)
{
    int idx = blockIdx.x * 256 + threadIdx.x;     // 0 .. 19200*768/4 - 1
    int row = idx / 192;                          // 192 float4 per row
    int c4  = (idx - row * 192) * 4;
    int n = row / 300, m = row - n * 300;
    float4 v = *(const float4*)(f + ((size_t)(n * 301 + m + 1)) * CC + c4);
    v4h h = { (_Float16)v.x, (_Float16)v.y, (_Float16)v.z, (_Float16)v.w };
    *(v4h*)(o + (size_t)row * CC + c4) = h;
}

__global__ __launch_bounds__(256)
void pack_w_k(const float* __restrict__ s, _Float16* __restrict__ o, int n4)
{
    int idx = blockIdx.x * 256 + threadIdx.x;
    if (idx >= n4) return;
    float4 v = *(const float4*)(s + (size_t)idx * 4);
    v4h h = { (_Float16)v.x, (_Float16)v.y, (_Float16)v.z, (_Float16)v.w };
    *(v4h*)(o + (size_t)idx * 4) = h;
}

// ---------------------------------------------------------------------------
// transpose fc0_w (1536x768) -> w1t16 (768x1536) fp16, 64x64 LDS tiles.
// ---------------------------------------------------------------------------
__global__ __launch_bounds__(256)
void transpose_w1_k(const float* __restrict__ w1, _Float16* __restrict__ o)
{
    __shared__ float T[64][65];
    const int c0 = blockIdx.x * 64, e0 = blockIdx.y * 64;
    const int tc = threadIdx.x & 63, te = threadIdx.x >> 6;
    #pragma unroll
    for (int r = 0; r < 16; ++r) {
        int el = te * 16 + r;
        T[el][tc] = w1[(size_t)(e0 + el) * CC + c0 + tc];
    }
    __syncthreads();
    #pragma unroll
    for (int r = 0; r < 16; ++r) {
        int cl = te * 16 + r;
        o[(size_t)(c0 + cl) * EE + e0 + tc] = (_Float16)T[tc][cl];
    }
}

// ---------------------------------------------------------------------------
// composed biases: f<512: biasc[f] = dot(fcgk_w[f,:], fc0_b) + fcgk_b[f]
//                  f>=512: g=f-512: biasc[f] = dot(fcg_w[g,:], fc0_b) + fcg_b[g]
// one block per f, 256-thread reduction over 1536.
// ---------------------------------------------------------------------------
__global__ __launch_bounds__(256)
void biasc_k(const float* __restrict__ w2, const float* __restrict__ b2,
             const float* __restrict__ wg, const float* __restrict__ bg,
             const float* __restrict__ b0, float* __restrict__ biasc)
{
    int f = blockIdx.x;
    const float* row = (f < FF) ? (w2 + (size_t)f * EE) : (wg + (size_t)(f - FF) * EE);
    float s = 0.f;
    for (int e = threadIdx.x; e < EE; e += 256) s += row[e] * b0[e];
    __shared__ float red[256];
    red[threadIdx.x] = s;
    __syncthreads();
    for (int o = 128; o; o >>= 1) {
        if (threadIdx.x < o) red[threadIdx.x] += red[threadIdx.x + o];
        __syncthreads();
    }
    if (threadIdx.x == 0)
        biasc[f] = red[0] + ((f < FF) ? b2[f] : bg[f - FF]);
}

// ---------------------------------------------------------------------------
// Wgc[g,c] = sum_e fcg_w[g,e] * fc0_w[e,c]   (8 x 768, fp32)
// grid 12 blocks x 64 c each; 4 e-quarters per block.
// ---------------------------------------------------------------------------
__global__ __launch_bounds__(256)
void wgc_k(const float* __restrict__ wg, const float* __restrict__ w1,
           float* __restrict__ wgc)
{
    const int c = blockIdx.x * 64 + (threadIdx.x & 63);
    const int q = threadIdx.x >> 6;
    float acc[GG] = {};
    for (int e = q * 384; e < q * 384 + 384; ++e) {
        float w1v = w1[(size_t)e * CC + c];
        #pragma unroll
        for (int g = 0; g < GG; ++g) acc[g] = fmaf(wg[g * EE + e], w1v, acc[g]);
    }
    __shared__ float red[4][GG][64];
    #pragma unroll
    for (int g = 0; g < GG; ++g) red[q][g][threadIdx.x & 63] = acc[g];
    __syncthreads();
    if (threadIdx.x < 64) {
        #pragma unroll
        for (int g = 0; g < GG; ++g)
            wgc[g * CC + c] = red[0][g][threadIdx.x] + red[1][g][threadIdx.x]
                            + red[2][g][threadIdx.x] + red[3][g][threadIdx.x];
    }
}

// ---------------------------------------------------------------------------
// MFMA fp16 GEMM:  C[i,j] = sum_k A[i,k]*B[j,k] (+ bias[j])  (both K-contig)
// 128x128 tile, BK=32, 4 waves (2x2 of 64x64), 4x4 16x16x32 MFMAs/wave.
// LDS XOR swizzle: chunk c of row r stored at slot c ^ ((r>>1)&3) -> fragment
// ds_read_b128 is 2-way bank aliased (free) instead of 8-way.
// OUTF16: fp16 out. BN0+SOFTGATE: (v+b)*bn -> softmax over wave's 64-col
// group * sigmoid gate -> out.
// ---------------------------------------------------------------------------
template<bool OUTF16, bool BN0, bool SOFTGATE, bool BIAS>
__global__ __launch_bounds__(256)
void hgemm_nt(const _Float16* __restrict__ A, const _Float16* __restrict__ B,
              const float* __restrict__ bias,
              const float* __restrict__ bn_g, const float* __restrict__ bn_b,
              const float* __restrict__ sig,
              void* __restrict__ Cout, int Ndim, int Kdim)
{
    __shared__ _Float16 As[128 * 32];   // [row][32], 64 B/row, chunk-swizzled
    __shared__ _Float16 Bs[128 * 32];

    const int tid  = threadIdx.x;
    const int wave = tid >> 6, lane = tid & 63;
    const int wr   = wave >> 1, wc = wave & 1;
    const int row0 = blockIdx.y * 128, col0 = blockIdx.x * 128;

    // staging: slot l' -> row r=l'>>2, stored chunk cs=l'&3, src chunk cs^((r>>1)&3)
    const int r0 = tid >> 2, cs = tid & 3;
    const int cc = cs ^ ((r0 >> 1) & 3);     // same for r0+64 (64>>1 = 32, &3 = 0)
    const _Float16* ga0 = A + (size_t)(row0 + r0) * Kdim + cc * 8;
    const _Float16* ga1 = A + (size_t)(row0 + r0 + 64) * Kdim + cc * 8;
    const _Float16* gb0 = B + (size_t)(col0 + r0) * Kdim + cc * 8;
    const _Float16* gb1 = B + (size_t)(col0 + r0 + 64) * Kdim + cc * 8;
    _Float16* sa0 = As + wave * 512;
    _Float16* sa1 = As + 2048 + wave * 512;
    _Float16* sb0 = Bs + wave * 512;
    _Float16* sb1 = Bs + 2048 + wave * 512;

    v4f acc[4][4];
    #pragma unroll
    for (int i = 0; i < 4; ++i)
        #pragma unroll
        for (int j = 0; j < 4; ++j)
            acc[i][j] = (v4f){0.f, 0.f, 0.f, 0.f};

    const int fm = lane & 15, fq = lane >> 4;
    const int sw = (fm >> 1) & 3;            // row-swizzle key (rows step 16)
    const _Float16* arp = As + (wr * 64 + fm) * 32 + (fq ^ sw) * 8;
    const _Float16* brp = Bs + (wc * 64 + fm) * 32 + (fq ^ sw) * 8;

    for (int kt = 0; kt < Kdim; kt += 32) {
        GLOAD_LDS16(ga0 + kt, sa0);
        GLOAD_LDS16(ga1 + kt, sa1);
        GLOAD_LDS16(gb0 + kt, sb0);
        GLOAD_LDS16(gb1 + kt, sb1);
        __syncthreads();

        v8h af[4], bf[4];
        #pragma unroll
        for (int i = 0; i < 4; ++i) af[i] = *(const v8h*)(arp + i * 16 * 32);
        #pragma unroll
        for (int j = 0; j < 4; ++j) bf[j] = *(const v8h*)(brp + j * 16 * 32);
        #pragma unroll
        for (int i = 0; i < 4; ++i)
            #pragma unroll
            for (int j = 0; j < 4; ++j)
                acc[i][j] = __builtin_amdgcn_mfma_f32_16x16x32_f16(
                    af[i], bf[j], acc[i][j], 0, 0, 0);
        __syncthreads();
    }

    // epilogue: D col = fm + j*16 (B side), row = fq*4 + r + i*16 (A side)
    float bj[4];
    #pragma unroll
    for (int j = 0; j < 4; ++j)
        bj[j] = BIAS ? bias[col0 + wc * 64 + j * 16 + fm] : 0.f;

    if (SOFTGATE) {
        const int gidx = (col0 >> 6) + wc;     // softmax group of this wave
        #pragma unroll
        for (int i = 0; i < 4; ++i) {
            #pragma unroll
            for (int r = 0; r < 4; ++r) {
                int grow = row0 + wr * 64 + i * 16 + fq * 4 + r;
                int n = grow / 300, mm = grow - n * 300;
                float g = bn_g[mm], bb = bn_b[mm];
                float v[4];
                #pragma unroll
                for (int j = 0; j < 4; ++j)
                    v[j] = (acc[i][j][r] + bj[j]) * g + bb;
                float mx = fmaxf(fmaxf(v[0], v[1]), fmaxf(v[2], v[3]));
                #pragma unroll
                for (int w = 1; w < 16; w <<= 1) mx = fmaxf(mx, __shfl_xor(mx, w));
                float e[4], s = 0.f;
                #pragma unroll
                for (int j = 0; j < 4; ++j) { e[j] = __expf(v[j] - mx); s += e[j]; }
                #pragma unroll
                for (int w = 1; w < 16; w <<= 1) s += __shfl_xor(s, w);
                float gate = sig[(size_t)grow * GG + gidx];
                float inv = gate / s;
                if (OUTF16) {
                    _Float16* cp = (_Float16*)Cout + (size_t)grow * Ndim + col0 + wc * 64;
                    #pragma unroll
                    for (int j = 0; j < 4; ++j) cp[j * 16 + fm] = (_Float16)(e[j] * inv);
                } else {
                    float* cp = (float*)Cout + (size_t)grow * Ndim + col0 + wc * 64;
                    #pragma unroll
                    for (int j = 0; j < 4; ++j) cp[j * 16 + fm] = e[j] * inv;
                }
            }
        }
        return;
    }

    #pragma unroll
    for (int i = 0; i < 4; ++i) {
        #pragma unroll
        for (int r = 0; r < 4; ++r) {
            int grow = row0 + wr * 64 + i * 16 + fq * 4 + r;
            float g = 1.f, bb = 0.f;
            if (BN0) { int m = grow % 300; g = bn_g[m]; bb = bn_b[m]; }
            #pragma unroll
            for (int j = 0; j < 4; ++j) {
                int gcol = col0 + wc * 64 + j * 16 + fm;
                float v = acc[i][j][r] + bj[j];
                if (BN0) v = v * g + bb;
                if (OUTF16)
                    ((_Float16*)Cout)[(size_t)grow * Ndim + gcol] = (_Float16)v;
                else
                    ((float*)Cout)[(size_t)grow * Ndim + gcol] = v;
            }
        }
    }
}

// ---------------------------------------------------------------------------
// alpha_g from xf16 with composed Wgc (8x768 fp32 in LDS) + composed bias.
// sig[r*8+g] = sigmoid(dot(xf16[r,:768], Wgc[g,:]) + bgc[g])
// ---------------------------------------------------------------------------
__global__ __launch_bounds__(256)
void alpha_sig_k(const _Float16* __restrict__ x, const float* __restrict__ wgc,
                 const float* __restrict__ bgc, float* __restrict__ sig)
{
    __shared__ float W[GG * CC];   // 24 KB
    for (int i = threadIdx.x; i < GG * CC; i += 256) W[i] = wgc[i];
    __syncthreads();

    const int wave = threadIdx.x >> 6;
    const int lane = threadIdx.x & 63;

    for (int rr = 0; rr < 4; ++rr) {
        int row = blockIdx.x * 16 + wave * 4 + rr;
        const _Float16* xr = x + (size_t)row * CC;
        float acc[GG] = {};
        for (int c = lane; c < CC; c += 64) {
            float xv = (float)xr[c];
            #pragma unroll
            for (int g = 0; g < GG; ++g) acc[g] = fmaf(xv, W[g * CC + c], acc[g]);
        }
        float myval = 0.f;
        #pragma unroll
        for (int g = 0; g < GG; ++g) {
            float s = acc[g];
            #pragma unroll
            for (int o = 32; o; o >>= 1) s += __shfl_xor(s, o);
            if (lane == g) myval = s + bgc[g];
        }
        if (lane < GG) {
            sig[(size_t)row * GG + lane] = 1.f / (1.f + __expf(-myval));
        }
    }
}

// ---------------------------------------------------------------------------
// apart[ps,n,k] = sum_{p in ps*300..+300} act[n,p,k]   (act fp16)
// ---------------------------------------------------------------------------
__global__ __launch_bounds__(256)
void asum_ps_k(const _Float16* __restrict__ act, float* __restrict__ apart)
{
    const int ps = blockIdx.x, n = blockIdx.y;
    const int k = threadIdx.x & 63, q = threadIdx.x >> 6;
    const _Float16* base = act + ((size_t)n * PP + ps * 300 + q * 75) * 64 + k;
    float s = 0.f;
    for (int p = 0; p < 75; ++p) s += (float)base[(size_t)p * 64];
    __shared__ float part[4][64];
    part[q][k] = s;
    __syncthreads();
    if (threadIdx.x < 64)
        apart[((size_t)ps * NN + n) * 64 + threadIdx.x] =
            part[0][threadIdx.x] + part[1][threadIdx.x]
          + part[2][threadIdx.x] + part[3][threadIdx.x];
}

// ---------------------------------------------------------------------------
// vlad partial, split over P 8 ways (act fp16, x_dot fp16):
// part[ps,n,d,k] = sum_{p in [ps*300,+300)} act[n,p,k]*x_tilde[n,p,d]
// ---------------------------------------------------------------------------
__global__ __launch_bounds__(256)
void vlad_ps_k(const _Float16* __restrict__ act, const _Float16* __restrict__ xdot,
               float* __restrict__ part)
{
    const int dt = blockIdx.x, n = blockIdx.y, ps = blockIdx.z;
    const int d0 = dt * 64;
    const int p0 = ps * 300, pend = p0 + 300;
    __shared__ float As[16][64];
    __shared__ float Xs[16][64];
    const int tid = threadIdx.x;
    const int tx = tid & 15, ty = tid >> 4;
    const int kb = tx * 4, db = ty * 4;
    const _Float16* actn = act + (size_t)n * PP * 64;
    const _Float16* xn   = xdot + (size_t)n * MM * EE;
    float acc[4][4] = {};

    const int lpp = tid >> 4, lk4 = (tid & 15) << 2;
    for (int pc = p0; pc < pend; pc += 16) {
        int p = pc + lpp;
        float a0 = 0.f, a1 = 0.f, a2 = 0.f, a3 = 0.f;
        float x0 = 0.f, x1 = 0.f, x2 = 0.f, x3 = 0.f;
        if (p < pend) {
            v4h avh = *(const v4h*)(actn + (size_t)p * 64 + lk4);
            a0 = (float)avh[0]; a1 = (float)avh[1]; a2 = (float)avh[2]; a3 = (float)avh[3];
            v4h xv = *(const v4h*)(xn + (size_t)(p >> 3) * EE + (p & 7) * GS + d0 + lk4);
            x0 = (float)xv[0]; x1 = (float)xv[1]; x2 = (float)xv[2]; x3 = (float)xv[3];
        }
        As[lpp][lk4 + 0] = a0; As[lpp][lk4 + 1] = a1;
        As[lpp][lk4 + 2] = a2; As[lpp][lk4 + 3] = a3;
        Xs[lpp][lk4 + 0] = x0; Xs[lpp][lk4 + 1] = x1;
        Xs[lpp][lk4 + 2] = x2; Xs[lpp][lk4 + 3] = x3;
        __syncthreads();
        #pragma unroll
        for (int q = 0; q < 16; ++q) {
            float4 a4 = *(const float4*)&As[q][kb];
            float4 x4 = *(const float4*)&Xs[q][db];
            float aa[4] = {a4.x, a4.y, a4.z, a4.w};
            float xx[4] = {x4.x, x4.y, x4.z, x4.w};
            #pragma unroll
            for (int i = 0; i < 4; ++i)
                #pragma unroll
                for (int j = 0; j < 4; ++j)
                    acc[i][j] = fmaf(xx[i], aa[j], acc[i][j]);
        }
        __syncthreads();
    }

    float* pp = part + ((size_t)ps * NN + n) * DESC;
    #pragma unroll
    for (int i = 0; i < 4; ++i) {
        int dd = d0 + db + i;
        float4 o = {acc[i][0], acc[i][1], acc[i][2], acc[i][3]};
        *(float4*)(pp + (size_t)dd * 64 + kb) = o;
    }
}

// ---------------------------------------------------------------------------
// vlad[n,d,k] = sum_ps part[ps,n,d,k] - (sum_ps apart[ps,n,k])*cw2[d,k]
// ---------------------------------------------------------------------------
__global__ __launch_bounds__(256)
void vlad_reduce_k(const float* __restrict__ part, const float* __restrict__ apart,
                   const float* __restrict__ cw2, float* __restrict__ vlad)
{
    int idx = blockIdx.x * 256 + threadIdx.x;   // (n*192+d)*64+k
    float s = 0.f;
    #pragma unroll
    for (int ps = 0; ps < 8; ++ps) s += part[(size_t)ps * (NN * DESC) + idx];
    int k = idx & 63;
    int d = (idx >> 6) % GS;
    int n = idx / DESC;
    float a = 0.f;
    #pragma unroll
    for (int ps = 0; ps < 8; ++ps) a += apart[((size_t)ps * NN + n) * 64 + k];
    vlad[idx] = s - a * cw2[d * 64 + k];
}

// ---------------------------------------------------------------------------
// intra-norm over d (192) per (n,k), then *bn1_g + bn1_b, in place.
// ---------------------------------------------------------------------------
__global__ __launch_bounds__(256)
void norm_k(float* __restrict__ vlad, const float* __restrict__ bn1g,
            const float* __restrict__ bn1b)
{
    int n = blockIdx.x;
    float* v = vlad + (size_t)n * DESC;
    int k = threadIdx.x & 63, q = threadIdx.x >> 6;
    float s = 0.f;
    for (int d = q * 48; d < q * 48 + 48; ++d) s += fabsf(v[d * 64 + k]);
    __shared__ float part[4][64];
    __shared__ float inv[64];
    part[q][k] = s;
    __syncthreads();
    if (threadIdx.x < 64) {
        float t = part[0][threadIdx.x] + part[1][threadIdx.x]
                + part[2][threadIdx.x] + part[3][threadIdx.x];
        inv[threadIdx.x] = 1.f / fmaxf(t, 1e-12f);
    }
    __syncthreads();
    float g = bn1g[0], b = bn1b[0];
    for (int idx = threadIdx.x; idx < DESC; idx += 256) {
        v[idx] = v[idx] * inv[idx & 63] * g + b;
    }
}

// ---------------------------------------------------------------------------
// cls_fc split-K: part[ks, n, b] = sum_{k chunk} vlad[n,k]*W[b,k]
// ---------------------------------------------------------------------------
__global__ __launch_bounds__(256)
void fsplit_k(const float* __restrict__ vlad, const float* __restrict__ W,
              float* __restrict__ part)
{
    const int bcol0 = (blockIdx.x & 7) * 64;
    const int ks = blockIdx.x >> 3;
    const int kc0 = ks * 256;
    __shared__ float Vs[32][68];
    __shared__ float Ws[32][68];
    const int tid = threadIdx.x, tx = tid & 15, ty = tid >> 4;
    float acc[4][4] = {};

    for (int kc = kc0; kc < kc0 + 256; kc += 32) {
        #pragma unroll
        for (int it = 0; it < 2; ++it) {
            int sl = tid + it * 256;
            int rr = sl >> 3, k4 = (sl & 7) << 2;
            float4 v = *(const float4*)(vlad + (size_t)rr * DESC + kc + k4);
            Vs[k4+0][rr] = v.x; Vs[k4+1][rr] = v.y; Vs[k4+2][rr] = v.z; Vs[k4+3][rr] = v.w;
            float4 w = *(const float4*)(W + (size_t)(bcol0 + rr) * DESC + kc + k4);
            Ws[k4+0][rr] = w.x; Ws[k4+1][rr] = w.y; Ws[k4+2][rr] = w.z; Ws[k4+3][rr] = w.w;
        }
        __syncthreads();
        #pragma unroll
        for (int q = 0; q < 32; ++q) {
            float4 wv = *(const float4*)&Ws[q][tx*4];
            float4 vv = *(const float4*)&Vs[q][ty*4];
            float wa[4] = {wv.x, wv.y, wv.z, wv.w};
            float va[4] = {vv.x, vv.y, vv.z, vv.w};
            #pragma unroll
            for (int i = 0; i < 4; ++i)
                #pragma unroll
                for (int j = 0; j < 4; ++j)
                    acc[i][j] = fmaf(va[i], wa[j], acc[i][j]);
        }
        __syncthreads();
    }
    float* p = part + (size_t)ks * (NN * NB);
    #pragma unroll
    for (int i = 0; i < 4; ++i) {
        int n = ty * 4 + i;
        float4 o = {acc[i][0], acc[i][1], acc[i][2], acc[i][3]};
        *(float4*)(p + (size_t)n * NB + bcol0 + tx*4) = o;
    }
}

__global__ __launch_bounds__(256)
void freduce_k(const float* __restrict__ part, const float* __restrict__ bias,
               const float* __restrict__ bng, const float* __restrict__ bnb,
               float* __restrict__ f)
{
    int idx = blockIdx.x * 256 + threadIdx.x;  // 0..32767
    float s = 0.f;
    for (int ks = 0; ks < 48; ++ks) s += part[(size_t)ks * (NN * NB) + idx];
    int b = idx & (NB - 1);
    f[idx] = (s + bias[b]) * bng[b] + bnb[b];
}

// ---------------------------------------------------------------------------
// cls[n,c] = dot(f[n,:512], cls_w[c,:512]) + cls_b[c]
// ---------------------------------------------------------------------------
__global__ __launch_bounds__(256)
void cls_k(const float* __restrict__ f, const float* __restrict__ W,
           const float* __restrict__ bias, float* __restrict__ out)
{
    const int c0 = blockIdx.x * 64;
    __shared__ float Fs[32][68];
    __shared__ float Ws[32][68];
    const int tid = threadIdx.x, tx = tid & 15, ty = tid >> 4;
    float acc[4][4] = {};

    for (int kc = 0; kc < NB; kc += 32) {
        #pragma unroll
        for (int it = 0; it < 2; ++it) {
            int sl = tid + it * 256;
            int rr = sl >> 3, k4 = (sl & 7) << 2;
            float4 v = *(const float4*)(f + (size_t)rr * NB + kc + k4);
            Fs[k4+0][rr] = v.x; Fs[k4+1][rr] = v.y; Fs[k4+2][rr] = v.z; Fs[k4+3][rr] = v.w;
            int c = c0 + rr;
            float4 w = (c < NCLS) ? *(const float4*)(W + (size_t)c * NB + kc + k4)
                                  : make_float4(0.f, 0.f, 0.f, 0.f);
            Ws[k4+0][rr] = w.x; Ws[k4+1][rr] = w.y; Ws[k4+2][rr] = w.z; Ws[k4+3][rr] = w.w;
        }
        __syncthreads();
        #pragma unroll
        for (int q = 0; q < 32; ++q) {
            float4 wv = *(const float4*)&Ws[q][tx*4];
            float4 fv = *(const float4*)&Fs[q][ty*4];
            float wa[4] = {wv.x, wv.y, wv.z, wv.w};
            float fa[4] = {fv.x, fv.y, fv.z, fv.w};
            #pragma unroll
            for (int i = 0; i < 4; ++i)
                #pragma unroll
                for (int j = 0; j < 4; ++j)
                    acc[i][j] = fmaf(fa[i], wa[j], acc[i][j]);
        }
        __syncthreads();
    }
    #pragma unroll
    for (int i = 0; i < 4; ++i) {
        int n = ty * 4 + i;
        #pragma unroll
        for (int j = 0; j < 4; ++j) {
            int c = c0 + tx * 4 + j;
            if (c < NCLS) out[(size_t)n * NCLS + c] = acc[i][j] + bias[c];
        }
    }
}

// ---------------------------------------------------------------------------
extern "C" void kernel_launch(void* const* d_in, const int* in_sizes, int n_in,
                              void* d_out, int out_size, void* d_ws, size_t ws_size,
                              hipStream_t stream)
{
    const float* features = (const float*)d_in[0];
    const float* fc0_w    = (const float*)d_in[1];
    const float* fc0_b    = (const float*)d_in[2];
    const float* fcgk_w   = (const float*)d_in[3];
    const float* fcgk_b   = (const float*)d_in[4];
    const float* fcg_w    = (const float*)d_in[5];
    const float* fcg_b    = (const float*)d_in[6];
    const float* bn0_g    = (const float*)d_in[7];
    const float* bn0_b    = (const float*)d_in[8];
    const float* cw2      = (const float*)d_in[9];
    const float* bn1_g    = (const float*)d_in[10];
    const float* bn1_b    = (const float*)d_in[11];
    const float* cls_fc_w = (const float*)d_in[12];
    const float* cls_fc_b = (const float*)d_in[13];
    const float* cls_bn_g = (const float*)d_in[14];
    const float* cls_bn_b = (const float*)d_in[15];
    const float* cls_w    = (const float*)d_in[16];
    const float* cls_b    = (const float*)d_in[17];

    // Workspace layout (bytes). Total ~150.6 MB.
    char* ws = (char*)d_ws;
    _Float16* xf16   = (_Float16*)(ws + 0);            // 29,491,200
    _Float16* w1f16  = (_Float16*)(ws + 29491200);     //  2,359,296
    _Float16* w2f16  = (_Float16*)(ws + 31850496);     //  1,572,864
    _Float16* w1t16  = (_Float16*)(ws + 33423360);     //  2,359,296
    _Float16* w2cf16 = (_Float16*)(ws + 35782656);     //    786,432
    float*    biasc  = (float*)   (ws + 36569088);     //      4,096 (520 used)
    float*    wgc    = (float*)   (ws + 36573184);     //     24,576
    _Float16* xdot16 = (_Float16*)(ws + 36597760);     // 58,982,400
    _Float16* act16  = (_Float16*)(ws + 95580160);     // 19,660,800
    float*    sigma  = (float*)   (ws + 115240960);    //    614,400
    float*    apart  = (float*)   (ws + 115855360);    //    131,072
    float*    vpart  = (float*)   (ws + 115986432);    // 25,165,824
    float*    vlad   = (float*)   (ws + 141152256);    //  3,145,728
    float*    fpart  = (float*)   (ws + 144297984);    //  6,291,456 -> 150,589,440

    float* cls_out = (float*)d_out;          // 64*701
    float* f_out   = cls_out + NN * NCLS;    // 64*512

    dim3 blk(256);

    // 0. packs + weight composition
    pack_x_k<<<14400, blk, 0, stream>>>(features, xf16);
    pack_w_k<<<1152, blk, 0, stream>>>(fc0_w, w1f16, EE * CC / 4);
    pack_w_k<<<768, blk, 0, stream>>>(fcgk_w, w2f16, FF * EE / 4);
    transpose_w1_k<<<dim3(12, 24), blk, 0, stream>>>(fc0_w, w1t16);
    biasc_k<<<520, blk, 0, stream>>>(fcgk_w, fcgk_b, fcg_w, fcg_b, fc0_b, biasc);
    wgc_k<<<12, blk, 0, stream>>>(fcg_w, fc0_w, wgc);
    // W2c[f,c] = sum_e W2[f,e]*W1[e,c]  (512x768, K=1536) -> fp16
    hgemm_nt<true, false, false, false><<<dim3(6, 4), blk, 0, stream>>>(
        w2f16, w1t16, nullptr, nullptr, nullptr, nullptr, w2cf16, CC, EE);

    // 1. x_dot = x @ fc0_w^T + fc0_b  (19200x1536, K=768) -> fp16 (vlad only)
    hgemm_nt<true, false, false, true><<<dim3(12, 150), blk, 0, stream>>>(
        xf16, w1f16, fc0_b, nullptr, nullptr, nullptr, xdot16, EE, CC);

    // 2. alpha_g = sigmoid(x @ Wgc^T + bgc)
    alpha_sig_k<<<1200, blk, 0, stream>>>(xf16, wgc, biasc + FF, sigma);

    // 3. act = softmax((x @ W2c^T + biasc)*bn0) * gate  (19200x512, K=768) -> fp16
    hgemm_nt<true, true, true, true><<<dim3(4, 150), blk, 0, stream>>>(
        xf16, w2cf16, biasc, bn0_g, bn0_b, sigma, act16, FF, CC);

    // 4. apart[ps,n,k] = partial sums of act over p
    asum_ps_k<<<dim3(8, 64), blk, 0, stream>>>(act16, apart);

    // 5. vlad partials (split-P x8) + reduce with -a*cw2
    vlad_ps_k<<<dim3(3, 64, 8), blk, 0, stream>>>(act16, xdot16, vpart);
    vlad_reduce_k<<<3072, blk, 0, stream>>>(vpart, apart, cw2, vlad);

    // 6. intra-norm + bn1
    norm_k<<<64, blk, 0, stream>>>(vlad, bn1_g, bn1_b);

    // 7. f = vlad @ cls_fc_w^T (+bias)*bn
    fsplit_k<<<384, blk, 0, stream>>>(vlad, cls_fc_w, fpart);
    freduce_k<<<128, blk, 0, stream>>>(fpart, cls_fc_b, cls_bn_g, cls_bn_b, f_out);

    // 8. cls = f @ cls_w^T + cls_b
    cls_k<<<11, blk, 0, stream>>>(f_out, cls_w, cls_b, cls_out);
}

// Round 5
// 445.879 us; speedup vs baseline: 3.2089x; 1.1454x over previous
//
#include <hip/hip_runtime.h>
#include <hip/hip_bf16.h>

// NeXtVLAD forward. Round 5: launch-count reduction (17 -> 11 graph nodes).
// - setup_k fuses pack_x/pack_w1/pack_w2/transpose_w1/biasc/wgc (atomic).
// - alpha_sig folded as a grid tail of the GEMM1 launch.
// - vlad_ps + asum fused into one launch; vlad_reduce + norm fused into one.
// - cls via 44-block split-K atomics into zeroed d_out.
#define NN 64
#define MM 300
#define CC 768
#define EE 1536          // LAMB*C
#define GG 8
#define KK 64
#define FF 512           // G*K
#define GS 192           // LAMB*C/G
#define PP 2400          // M*G
#define DESC 12288       // K*GS
#define NMROWS 19200     // N*M
#define NB 512
#define NCLS 701

typedef _Float16 v8h __attribute__((ext_vector_type(8)));
typedef _Float16 v4h __attribute__((ext_vector_type(4)));
typedef float    v4f __attribute__((ext_vector_type(4)));

#define GLOAD_LDS16(g, s) \
    __builtin_amdgcn_global_load_lds( \
        (const __attribute__((address_space(1))) void*)(g), \
        (__attribute__((address_space(3))) void*)(s), 16, 0, 0)

// ---------------------------------------------------------------------------
// setup_k: fused preprocessing, branch on blockIdx ranges (all independent).
//  [0,14400)        pack features[:,1:] -> xf16
//  [14400,15552)    pack fc0_w -> w1f16
//  [15552,16320)    pack fcgk_w -> w2f16
//  [16320,16608)    transpose fc0_w -> w1t16 (768x1536 fp16)
//  [16608,17128)    composed biases biasc[520]
//  [17128,17224)    Wgc[g,c] = fcg_w@fc0_w (atomicAdd, wgc pre-zeroed)
// ---------------------------------------------------------------------------
__global__ __launch_bounds__(256)
void setup_k(const float* __restrict__ features, const float* __restrict__ fc0_w,
             const float* __restrict__ fcgk_w, const float* __restrict__ fcg_w,
             const float* __restrict__ fc0_b, const float* __restrict__ fcgk_b,
             const float* __restrict__ fcg_b,
             _Float16* __restrict__ xf16, _Float16* __restrict__ w1f16,
             _Float16* __restrict__ w2f16, _Float16* __restrict__ w1t16,
             float* __restrict__ biasc, float* __restrict__ wgc)
{
    __shared__ __align__(16) char sm[16640];
    const int bid = blockIdx.x, tid = threadIdx.x;

    if (bid < 14400) {                       // pack_x
        int idx = bid * 256 + tid;
        int row = idx / 192;
        int c4  = (idx - row * 192) * 4;
        int n = row / 300, m = row - n * 300;
        float4 v = *(const float4*)(features + ((size_t)(n * 301 + m + 1)) * CC + c4);
        v4h h = { (_Float16)v.x, (_Float16)v.y, (_Float16)v.z, (_Float16)v.w };
        *(v4h*)(xf16 + (size_t)row * CC + c4) = h;
        return;
    }
    if (bid < 15552) {                       // pack w1
        int idx = (bid - 14400) * 256 + tid;
        float4 v = *(const float4*)(fc0_w + (size_t)idx * 4);
        v4h h = { (_Float16)v.x, (_Float16)v.y, (_Float16)v.z, (_Float16)v.w };
        *(v4h*)(w1f16 + (size_t)idx * 4) = h;
        return;
    }
    if (bid < 16320) {                       // pack w2
        int idx = (bid - 15552) * 256 + tid;
        float4 v = *(const float4*)(fcgk_w + (size_t)idx * 4);
        v4h h = { (_Float16)v.x, (_Float16)v.y, (_Float16)v.z, (_Float16)v.w };
        *(v4h*)(w2f16 + (size_t)idx * 4) = h;
        return;
    }
    if (bid < 16608) {                       // transpose w1 -> w1t16
        float (*T)[65] = (float(*)[65])sm;
        int b = bid - 16320;
        const int c0 = (b % 12) * 64, e0 = (b / 12) * 64;
        const int tc = tid & 63, te = tid >> 6;
        #pragma unroll
        for (int r = 0; r < 16; ++r) {
            int el = te * 16 + r;
            T[el][tc] = fc0_w[(size_t)(e0 + el) * CC + c0 + tc];
        }
        __syncthreads();
        #pragma unroll
        for (int r = 0; r < 16; ++r) {
            int cl = te * 16 + r;
            w1t16[(size_t)(c0 + cl) * EE + e0 + tc] = (_Float16)T[tc][cl];
        }
        return;
    }
    if (bid < 17128) {                       // composed biases
        float* red = (float*)sm;
        int f = bid - 16608;
        const float* row = (f < FF) ? (fcgk_w + (size_t)f * EE)
                                    : (fcg_w + (size_t)(f - FF) * EE);
        float s = 0.f;
        for (int e = tid; e < EE; e += 256) s += row[e] * fc0_b[e];
        red[tid] = s;
        __syncthreads();
        for (int o = 128; o; o >>= 1) {
            if (tid < o) red[tid] += red[tid + o];
            __syncthreads();
        }
        if (tid == 0)
            biasc[f] = red[0] + ((f < FF) ? fcgk_b[f] : fcg_b[f - FF]);
        return;
    }
    {                                        // Wgc, 8-way e-split + atomics
        float (*red)[GG][64] = (float(*)[GG][64])sm;
        int b = bid - 17128;                 // 0..95
        const int c = (b % 12) * 64 + (tid & 63);
        const int es = b / 12, q = tid >> 6;
        float acc[GG] = {};
        for (int e = es * 192 + q * 48; e < es * 192 + q * 48 + 48; ++e) {
            float w1v = fc0_w[(size_t)e * CC + c];
            #pragma unroll
            for (int g = 0; g < GG; ++g) acc[g] = fmaf(fcg_w[g * EE + e], w1v, acc[g]);
        }
        #pragma unroll
        for (int g = 0; g < GG; ++g) red[q][g][tid & 63] = acc[g];
        __syncthreads();
        if (tid < 64) {
            #pragma unroll
            for (int g = 0; g < GG; ++g) {
                float v = red[0][g][tid] + red[1][g][tid] + red[2][g][tid] + red[3][g][tid];
                atomicAdd(&wgc[g * CC + c], v);
            }
        }
        return;
    }
}

// ---------------------------------------------------------------------------
// MFMA fp16 GEMM (1D grid, bx=bid%gx, by=bid/gx):
//   C[i,j] = sum_k A[i,k]*B[j,k] (+bias[j]); 128x128 tile, BK=32, XOR-swizzled
//   LDS, 4 waves, 4x4 16x16x32 MFMAs per wave.
// ALPHA: blocks bid>=gemm_blocks instead compute
//   sigout[r*8+g] = sigmoid(dot(A[r,:768], wgc[g,:]) + bgc[g])  (alpha_sig tail)
// SOFTGATE: epilogue (v+bias)*bn -> softmax over wave's 64-col group * gate.
// ---------------------------------------------------------------------------
template<bool OUTF16, bool BN0, bool SOFTGATE, bool BIAS, bool ALPHA>
__global__ __launch_bounds__(256)
void hgemm_nt(const _Float16* __restrict__ A, const _Float16* __restrict__ B,
              const float* __restrict__ bias,
              const float* __restrict__ bn_g, const float* __restrict__ bn_b,
              const float* __restrict__ sig,
              void* __restrict__ Cout, int Ndim, int Kdim, int gx,
              int gemm_blocks,
              const float* __restrict__ wgc, const float* __restrict__ bgc,
              float* __restrict__ sigout)
{
    __shared__ __align__(16) char smem[24576];
    const int tid  = threadIdx.x;
    const int bid  = blockIdx.x;
    const int wave = tid >> 6, lane = tid & 63;

    if (ALPHA && bid >= gemm_blocks) {
        // ---- alpha_sig tail: 16 rows per block ----
        float* Wl = (float*)smem;            // 8x768 fp32 = 24 KB
        for (int i = tid; i < GG * CC; i += 256) Wl[i] = wgc[i];
        __syncthreads();
        const int abid = bid - gemm_blocks;
        for (int rr = 0; rr < 4; ++rr) {
            int row = abid * 16 + wave * 4 + rr;
            const _Float16* xr = A + (size_t)row * CC;
            float acc[GG] = {};
            for (int c = lane; c < CC; c += 64) {
                float xv = (float)xr[c];
                #pragma unroll
                for (int g = 0; g < GG; ++g) acc[g] = fmaf(xv, Wl[g * CC + c], acc[g]);
            }
            float myval = 0.f;
            #pragma unroll
            for (int g = 0; g < GG; ++g) {
                float s = acc[g];
                #pragma unroll
                for (int o = 32; o; o >>= 1) s += __shfl_xor(s, o);
                if (lane == g) myval = s + bgc[g];
            }
            if (lane < GG)
                sigout[(size_t)row * GG + lane] = 1.f / (1.f + __expf(-myval));
        }
        return;
    }

    _Float16* As = (_Float16*)smem;          // 128x32, 8 KB
    _Float16* Bs = (_Float16*)(smem + 8192);

    const int bx = bid % gx, by = bid / gx;
    const int wr = wave >> 1, wc = wave & 1;
    const int row0 = by * 128, col0 = bx * 128;

    // staging: slot l -> row r=l>>2, stored chunk cs=l&3, src chunk cs^((r>>1)&3)
    const int r0 = tid >> 2, cs = tid & 3;
    const int cc = cs ^ ((r0 >> 1) & 3);
    const _Float16* ga0 = A + (size_t)(row0 + r0) * Kdim + cc * 8;
    const _Float16* ga1 = A + (size_t)(row0 + r0 + 64) * Kdim + cc * 8;
    const _Float16* gb0 = B + (size_t)(col0 + r0) * Kdim + cc * 8;
    const _Float16* gb1 = B + (size_t)(col0 + r0 + 64) * Kdim + cc * 8;
    _Float16* sa0 = As + wave * 512;
    _Float16* sa1 = As + 2048 + wave * 512;
    _Float16* sb0 = Bs + wave * 512;
    _Float16* sb1 = Bs + 2048 + wave * 512;

    v4f acc[4][4];
    #pragma unroll
    for (int i = 0; i < 4; ++i)
        #pragma unroll
        for (int j = 0; j < 4; ++j)
            acc[i][j] = (v4f){0.f, 0.f, 0.f, 0.f};

    const int fm = lane & 15, fq = lane >> 4;
    const int sw = (fm >> 1) & 3;
    const _Float16* arp = As + (wr * 64 + fm) * 32 + (fq ^ sw) * 8;
    const _Float16* brp = Bs + (wc * 64 + fm) * 32 + (fq ^ sw) * 8;

    for (int kt = 0; kt < Kdim; kt += 32) {
        GLOAD_LDS16(ga0 + kt, sa0);
        GLOAD_LDS16(ga1 + kt, sa1);
        GLOAD_LDS16(gb0 + kt, sb0);
        GLOAD_LDS16(gb1 + kt, sb1);
        __syncthreads();

        v8h af[4], bf[4];
        #pragma unroll
        for (int i = 0; i < 4; ++i) af[i] = *(const v8h*)(arp + i * 16 * 32);
        #pragma unroll
        for (int j = 0; j < 4; ++j) bf[j] = *(const v8h*)(brp + j * 16 * 32);
        #pragma unroll
        for (int i = 0; i < 4; ++i)
            #pragma unroll
            for (int j = 0; j < 4; ++j)
                acc[i][j] = __builtin_amdgcn_mfma_f32_16x16x32_f16(
                    af[i], bf[j], acc[i][j], 0, 0, 0);
        __syncthreads();
    }

    float bj[4];
    #pragma unroll
    for (int j = 0; j < 4; ++j)
        bj[j] = BIAS ? bias[col0 + wc * 64 + j * 16 + fm] : 0.f;

    if (SOFTGATE) {
        const int gidx = (col0 >> 6) + wc;
        #pragma unroll
        for (int i = 0; i < 4; ++i) {
            #pragma unroll
            for (int r = 0; r < 4; ++r) {
                int grow = row0 + wr * 64 + i * 16 + fq * 4 + r;
                int n = grow / 300, mm = grow - n * 300;
                float g = bn_g[mm], bb = bn_b[mm];
                float v[4];
                #pragma unroll
                for (int j = 0; j < 4; ++j)
                    v[j] = (acc[i][j][r] + bj[j]) * g + bb;
                float mx = fmaxf(fmaxf(v[0], v[1]), fmaxf(v[2], v[3]));
                #pragma unroll
                for (int w = 1; w < 16; w <<= 1) mx = fmaxf(mx, __shfl_xor(mx, w));
                float e[4], s = 0.f;
                #pragma unroll
                for (int j = 0; j < 4; ++j) { e[j] = __expf(v[j] - mx); s += e[j]; }
                #pragma unroll
                for (int w = 1; w < 16; w <<= 1) s += __shfl_xor(s, w);
                float gate = sig[(size_t)grow * GG + gidx];
                float inv = gate / s;
                _Float16* cp = (_Float16*)Cout + (size_t)grow * Ndim + col0 + wc * 64;
                #pragma unroll
                for (int j = 0; j < 4; ++j) cp[j * 16 + fm] = (_Float16)(e[j] * inv);
            }
        }
        return;
    }

    #pragma unroll
    for (int i = 0; i < 4; ++i) {
        #pragma unroll
        for (int r = 0; r < 4; ++r) {
            int grow = row0 + wr * 64 + i * 16 + fq * 4 + r;
            float g = 1.f, bb = 0.f;
            if (BN0) { int m = grow % 300; g = bn_g[m]; bb = bn_b[m]; }
            #pragma unroll
            for (int j = 0; j < 4; ++j) {
                int gcol = col0 + wc * 64 + j * 16 + fm;
                float v = acc[i][j][r] + bj[j];
                if (BN0) v = v * g + bb;
                if (OUTF16)
                    ((_Float16*)Cout)[(size_t)grow * Ndim + gcol] = (_Float16)v;
                else
                    ((float*)Cout)[(size_t)grow * Ndim + gcol] = v;
            }
        }
    }
}

// ---------------------------------------------------------------------------
// vladact_k: fused vlad split-P partials [0,1536) + asum partials [1536,2048).
// vlad: part[ps,n,d,k] = sum_{p in [ps*300,+300)} act[n,p,k]*xt[n,p,d]
// asum: apart[ps,n,k]  = sum_{p in [ps*300,+300)} act[n,p,k]
// ---------------------------------------------------------------------------
__global__ __launch_bounds__(256)
void vladact_k(const _Float16* __restrict__ act, const _Float16* __restrict__ xdot,
               float* __restrict__ part, float* __restrict__ apart)
{
    __shared__ __align__(16) char sm[8192];
    const int tid = threadIdx.x, bid = blockIdx.x;

    if (bid >= 1536) {                       // ---- asum tail ----
        float (*red)[64] = (float(*)[64])sm;
        int b = bid - 1536;
        const int ps = b & 7, n = b >> 3;
        const int k = tid & 63, q = tid >> 6;
        const _Float16* base = act + ((size_t)n * PP + ps * 300 + q * 75) * 64 + k;
        float s = 0.f;
        for (int p = 0; p < 75; ++p) s += (float)base[(size_t)p * 64];
        red[q][k] = s;
        __syncthreads();
        if (tid < 64)
            apart[((size_t)ps * NN + n) * 64 + tid] =
                red[0][tid] + red[1][tid] + red[2][tid] + red[3][tid];
        return;
    }

    float (*As)[64] = (float(*)[64])sm;              // 16x64
    float (*Xs)[64] = (float(*)[64])(sm + 4096);
    const int dt = bid % 3, n = (bid / 3) & 63, ps = bid / 192;
    const int d0 = dt * 64;
    const int p0 = ps * 300, pend = p0 + 300;
    const int tx = tid & 15, ty = tid >> 4;
    const int kb = tx * 4, db = ty * 4;
    const _Float16* actn = act + (size_t)n * PP * 64;
    const _Float16* xn   = xdot + (size_t)n * MM * EE;
    float acc[4][4] = {};

    const int lpp = tid >> 4, lk4 = (tid & 15) << 2;
    for (int pc = p0; pc < pend; pc += 16) {
        int p = pc + lpp;
        float a0 = 0.f, a1 = 0.f, a2 = 0.f, a3 = 0.f;
        float x0 = 0.f, x1 = 0.f, x2 = 0.f, x3 = 0.f;
        if (p < pend) {
            v4h avh = *(const v4h*)(actn + (size_t)p * 64 + lk4);
            a0 = (float)avh[0]; a1 = (float)avh[1]; a2 = (float)avh[2]; a3 = (float)avh[3];
            v4h xv = *(const v4h*)(xn + (size_t)(p >> 3) * EE + (p & 7) * GS + d0 + lk4);
            x0 = (float)xv[0]; x1 = (float)xv[1]; x2 = (float)xv[2]; x3 = (float)xv[3];
        }
        As[lpp][lk4 + 0] = a0; As[lpp][lk4 + 1] = a1;
        As[lpp][lk4 + 2] = a2; As[lpp][lk4 + 3] = a3;
        Xs[lpp][lk4 + 0] = x0; Xs[lpp][lk4 + 1] = x1;
        Xs[lpp][lk4 + 2] = x2; Xs[lpp][lk4 + 3] = x3;
        __syncthreads();
        #pragma unroll
        for (int q = 0; q < 16; ++q) {
            float4 a4 = *(const float4*)&As[q][kb];
            float4 x4 = *(const float4*)&Xs[q][db];
            float aa[4] = {a4.x, a4.y, a4.z, a4.w};
            float xx[4] = {x4.x, x4.y, x4.z, x4.w};
            #pragma unroll
            for (int i = 0; i < 4; ++i)
                #pragma unroll
                for (int j = 0; j < 4; ++j)
                    acc[i][j] = fmaf(xx[i], aa[j], acc[i][j]);
        }
        __syncthreads();
    }

    float* pp = part + ((size_t)ps * NN + n) * DESC;
    #pragma unroll
    for (int i = 0; i < 4; ++i) {
        int dd = d0 + db + i;
        float4 o = {acc[i][0], acc[i][1], acc[i][2], acc[i][3]};
        *(float4*)(pp + (size_t)dd * 64 + kb) = o;
    }
}

// ---------------------------------------------------------------------------
// vladnorm_k: vlad[n,d,k] = (sum_ps part - a*cw2), then per-(n,k) L1 norm over
// d (192), scale by bn1. grid 256 = (n=64) x (kq=4, 16 k each); thread (td,tk)
// handles d = td*12..+12 for k = kq*16+tk; values stay in registers.
// ---------------------------------------------------------------------------
__global__ __launch_bounds__(256)
void vladnorm_k(const float* __restrict__ part, const float* __restrict__ apart,
                const float* __restrict__ cw2, const float* __restrict__ bn1g,
                const float* __restrict__ bn1b, float* __restrict__ vlad)
{
    const int n = blockIdx.x >> 2, kq = blockIdx.x & 3;
    const int tk = threadIdx.x & 15, td = threadIdx.x >> 4;
    const int k = kq * 16 + tk;

    float a = 0.f;
    #pragma unroll
    for (int ps = 0; ps < 8; ++ps) a += apart[((size_t)ps * NN + n) * 64 + k];

    float vloc[12];
    float sabs = 0.f;
    #pragma unroll
    for (int i = 0; i < 12; ++i) {
        int d = td * 12 + i;
        float s = 0.f;
        #pragma unroll
        for (int ps = 0; ps < 8; ++ps)
            s += part[((size_t)ps * NN + n) * DESC + (size_t)d * 64 + k];
        float v = s - a * cw2[d * 64 + k];
        vloc[i] = v;
        sabs += fabsf(v);
    }

    __shared__ float red[16][16];
    __shared__ float inv[16];
    red[td][tk] = sabs;
    __syncthreads();
    if (td == 0) {
        float t = 0.f;
        #pragma unroll
        for (int q = 0; q < 16; ++q) t += red[q][tk];
        inv[tk] = 1.f / fmaxf(t, 1e-12f);
    }
    __syncthreads();
    const float g = bn1g[0], b = bn1b[0];
    const float sc = inv[tk] * g;
    #pragma unroll
    for (int i = 0; i < 12; ++i) {
        int d = td * 12 + i;
        vlad[(size_t)n * DESC + (size_t)d * 64 + k] = vloc[i] * sc + b;
    }
}

// ---------------------------------------------------------------------------
// cls_fc split-K: fpart[ks, n, b] = sum_{k chunk} vlad[n,k]*W[b,k]
// ---------------------------------------------------------------------------
__global__ __launch_bounds__(256)
void fsplit_k(const float* __restrict__ vlad, const float* __restrict__ W,
              float* __restrict__ part)
{
    const int bcol0 = (blockIdx.x & 7) * 64;
    const int ks = blockIdx.x >> 3;
    const int kc0 = ks * 256;
    __shared__ float Vs[32][68];
    __shared__ float Ws[32][68];
    const int tid = threadIdx.x, tx = tid & 15, ty = tid >> 4;
    float acc[4][4] = {};

    for (int kc = kc0; kc < kc0 + 256; kc += 32) {
        #pragma unroll
        for (int it = 0; it < 2; ++it) {
            int sl = tid + it * 256;
            int rr = sl >> 3, k4 = (sl & 7) << 2;
            float4 v = *(const float4*)(vlad + (size_t)rr * DESC + kc + k4);
            Vs[k4+0][rr] = v.x; Vs[k4+1][rr] = v.y; Vs[k4+2][rr] = v.z; Vs[k4+3][rr] = v.w;
            float4 w = *(const float4*)(W + (size_t)(bcol0 + rr) * DESC + kc + k4);
            Ws[k4+0][rr] = w.x; Ws[k4+1][rr] = w.y; Ws[k4+2][rr] = w.z; Ws[k4+3][rr] = w.w;
        }
        __syncthreads();
        #pragma unroll
        for (int q = 0; q < 32; ++q) {
            float4 wv = *(const float4*)&Ws[q][tx*4];
            float4 vv = *(const float4*)&Vs[q][ty*4];
            float wa[4] = {wv.x, wv.y, wv.z, wv.w};
            float va[4] = {vv.x, vv.y, vv.z, vv.w};
            #pragma unroll
            for (int i = 0; i < 4; ++i)
                #pragma unroll
                for (int j = 0; j < 4; ++j)
                    acc[i][j] = fmaf(va[i], wa[j], acc[i][j]);
        }
        __syncthreads();
    }
    float* p = part + (size_t)ks * (NN * NB);
    #pragma unroll
    for (int i = 0; i < 4; ++i) {
        int n = ty * 4 + i;
        float4 o = {acc[i][0], acc[i][1], acc[i][2], acc[i][3]};
        *(float4*)(p + (size_t)n * NB + bcol0 + tx*4) = o;
    }
}

__global__ __launch_bounds__(256)
void freduce_k(const float* __restrict__ part, const float* __restrict__ bias,
               const float* __restrict__ bng, const float* __restrict__ bnb,
               float* __restrict__ f)
{
    int idx = blockIdx.x * 256 + threadIdx.x;  // 0..32767
    float s = 0.f;
    for (int ks = 0; ks < 48; ++ks) s += part[(size_t)ks * (NN * NB) + idx];
    int b = idx & (NB - 1);
    f[idx] = (s + bias[b]) * bng[b] + bnb[b];
}

// ---------------------------------------------------------------------------
// cls split-K (x4) with atomicAdd into zeroed d_out.
// grid 44 = 11 col-tiles x 4 k-splits of 128.
// ---------------------------------------------------------------------------
__global__ __launch_bounds__(256)
void cls_k(const float* __restrict__ f, const float* __restrict__ W,
           const float* __restrict__ bias, float* __restrict__ out)
{
    const int c0 = (blockIdx.x % 11) * 64;
    const int ks = blockIdx.x / 11;
    __shared__ float Fs[32][68];
    __shared__ float Ws[32][68];
    const int tid = threadIdx.x, tx = tid & 15, ty = tid >> 4;
    float acc[4][4] = {};

    for (int kc = ks * 128; kc < ks * 128 + 128; kc += 32) {
        #pragma unroll
        for (int it = 0; it < 2; ++it) {
            int sl = tid + it * 256;
            int rr = sl >> 3, k4 = (sl & 7) << 2;
            float4 v = *(const float4*)(f + (size_t)rr * NB + kc + k4);
            Fs[k4+0][rr] = v.x; Fs[k4+1][rr] = v.y; Fs[k4+2][rr] = v.z; Fs[k4+3][rr] = v.w;
            int c = c0 + rr;
            float4 w = (c < NCLS) ? *(const float4*)(W + (size_t)c * NB + kc + k4)
                                  : make_float4(0.f, 0.f, 0.f, 0.f);
            Ws[k4+0][rr] = w.x; Ws[k4+1][rr] = w.y; Ws[k4+2][rr] = w.z; Ws[k4+3][rr] = w.w;
        }
        __syncthreads();
        #pragma unroll
        for (int q = 0; q < 32; ++q) {
            float4 wv = *(const float4*)&Ws[q][tx*4];
            float4 fv = *(const float4*)&Fs[q][ty*4];
            float wa[4] = {wv.x, wv.y, wv.z, wv.w};
            float fa[4] = {fv.x, fv.y, fv.z, fv.w};
            #pragma unroll
            for (int i = 0; i < 4; ++i)
                #pragma unroll
                for (int j = 0; j < 4; ++j)
                    acc[i][j] = fmaf(fa[i], wa[j], acc[i][j]);
        }
        __syncthreads();
    }
    #pragma unroll
    for (int i = 0; i < 4; ++i) {
        int n = ty * 4 + i;
        #pragma unroll
        for (int j = 0; j < 4; ++j) {
            int c = c0 + tx * 4 + j;
            if (c < NCLS) {
                float v = acc[i][j] + ((ks == 0) ? bias[c] : 0.f);
                atomicAdd(&out[(size_t)n * NCLS + c], v);
            }
        }
    }
}

// ---------------------------------------------------------------------------
extern "C" void kernel_launch(void* const* d_in, const int* in_sizes, int n_in,
                              void* d_out, int out_size, void* d_ws, size_t ws_size,
                              hipStream_t stream)
{
    const float* features = (const float*)d_in[0];
    const float* fc0_w    = (const float*)d_in[1];
    const float* fc0_b    = (const float*)d_in[2];
    const float* fcgk_w   = (const float*)d_in[3];
    const float* fcgk_b   = (const float*)d_in[4];
    const float* fcg_w    = (const float*)d_in[5];
    const float* fcg_b    = (const float*)d_in[6];
    const float* bn0_g    = (const float*)d_in[7];
    const float* bn0_b    = (const float*)d_in[8];
    const float* cw2      = (const float*)d_in[9];
    const float* bn1_g    = (const float*)d_in[10];
    const float* bn1_b    = (const float*)d_in[11];
    const float* cls_fc_w = (const float*)d_in[12];
    const float* cls_fc_b = (const float*)d_in[13];
    const float* cls_bn_g = (const float*)d_in[14];
    const float* cls_bn_b = (const float*)d_in[15];
    const float* cls_w    = (const float*)d_in[16];
    const float* cls_b    = (const float*)d_in[17];

    // Workspace layout (bytes). Total ~150.6 MB.
    char* ws = (char*)d_ws;
    _Float16* xf16   = (_Float16*)(ws + 0);            // 29,491,200
    _Float16* w1f16  = (_Float16*)(ws + 29491200);     //  2,359,296
    _Float16* w2f16  = (_Float16*)(ws + 31850496);     //  1,572,864
    _Float16* w1t16  = (_Float16*)(ws + 33423360);     //  2,359,296
    _Float16* w2cf16 = (_Float16*)(ws + 35782656);     //    786,432
    float*    biasc  = (float*)   (ws + 36569088);     //      4,096 (520 used)
    float*    wgc    = (float*)   (ws + 36573184);     //     24,576
    _Float16* xdot16 = (_Float16*)(ws + 36597760);     // 58,982,400
    _Float16* act16  = (_Float16*)(ws + 95580160);     // 19,660,800
    float*    sigma  = (float*)   (ws + 115240960);    //    614,400
    float*    apart  = (float*)   (ws + 115855360);    //    131,072
    float*    vpart  = (float*)   (ws + 115986432);    // 25,165,824
    float*    vlad   = (float*)   (ws + 141152256);    //  3,145,728
    float*    fpart  = (float*)   (ws + 144297984);    //  6,291,456 -> 150,589,440

    float* cls_out = (float*)d_out;          // 64*701 (atomically accumulated)
    float* f_out   = cls_out + NN * NCLS;    // 64*512

    dim3 blk(256);

    // zero the atomic targets (graph-capturable async memsets)
    hipMemsetAsync(wgc, 0, GG * CC * sizeof(float), stream);
    hipMemsetAsync(cls_out, 0, (size_t)NN * NCLS * sizeof(float), stream);

    // 1. fused setup: packs + transpose + composed biases + Wgc
    setup_k<<<17224, blk, 0, stream>>>(features, fc0_w, fcgk_w, fcg_w,
                                       fc0_b, fcgk_b, fcg_b,
                                       xf16, w1f16, w2f16, w1t16, biasc, wgc);

    // 2. W2c[f,c] = W2@W1  (512x768, K=1536) -> fp16
    hgemm_nt<true, false, false, false, false><<<24, blk, 0, stream>>>(
        w2f16, w1t16, nullptr, nullptr, nullptr, nullptr, w2cf16,
        CC, EE, 6, 0, nullptr, nullptr, nullptr);

    // 3. x_dot = x @ W1^T + b0 (19200x1536, K=768) -> fp16  +  alpha_sig tail
    hgemm_nt<true, false, false, true, true><<<1800 + 1200, blk, 0, stream>>>(
        xf16, w1f16, fc0_b, nullptr, nullptr, nullptr, xdot16,
        EE, CC, 12, 1800, wgc, biasc + FF, sigma);

    // 4. act = softmax((x @ W2c^T + biasc)*bn0) * gate  (19200x512, K=768) -> fp16
    hgemm_nt<true, true, true, true, false><<<600, blk, 0, stream>>>(
        xf16, w2cf16, biasc, bn0_g, bn0_b, sigma, act16,
        FF, CC, 4, 0, nullptr, nullptr, nullptr);

    // 5. vlad partials (split-P x8) + asum partials, one launch
    vladact_k<<<2048, blk, 0, stream>>>(act16, xdot16, vpart, apart);

    // 6. reduce + (-a*cw2) + L1-norm + bn1, one kernel
    vladnorm_k<<<256, blk, 0, stream>>>(vpart, apart, cw2, bn1_g, bn1_b, vlad);

    // 7. f = vlad @ cls_fc_w^T (+bias)*bn
    fsplit_k<<<384, blk, 0, stream>>>(vlad, cls_fc_w, fpart);
    freduce_k<<<128, blk, 0, stream>>>(fpart, cls_fc_b, cls_bn_g, cls_bn_b, f_out);

    // 8. cls = f @ cls_w^T + cls_b  (split-K x4, atomic into zeroed out)
    cls_k<<<44, blk, 0, stream>>>(f_out, cls_w, cls_b, cls_out);
}